// Round 17
// baseline (376.931 us; speedup 1.0000x reference)
//
#include <hip/hip_runtime.h>

typedef unsigned int u32;
typedef unsigned short u16;
typedef unsigned long long u64;
typedef long i64;
typedef float f32x4 __attribute__((ext_vector_type(4)));
typedef float f32x2 __attribute__((ext_vector_type(2)));
typedef u32 u32x4 __attribute__((ext_vector_type(4)));

__device__ __forceinline__ u16 f2bf_rne(float f) {
    return __builtin_bit_cast(u16, (__bf16)f);
}
__device__ __forceinline__ float bf2f(u16 h) {
    return __builtin_bit_cast(float, ((u32)h) << 16);
}
__device__ __forceinline__ float gelu_fast(float v) {
    float t = __builtin_amdgcn_exp2f(v * -2.4554673f);
    return v * __builtin_amdgcn_rcpf(1.f + t);
}
__device__ __forceinline__ i64 mk64(u32 lo, u32 hi) {
    return (i64)(((u64)hi << 32) | (u64)lo);
}
__device__ __forceinline__ u32 pk4(float a, float b, float c, float d) {
    u32 w = (u32)__builtin_amdgcn_cvt_pk_fp8_f32(a, b, 0, false);
    return (u32)__builtin_amdgcn_cvt_pk_fp8_f32(c, d, (int)w, true);
}
__device__ __forceinline__ unsigned char f2fp8(float a) {
    u32 w = (u32)__builtin_amdgcn_cvt_pk_fp8_f32(a, 0.f, 0, false);
    return (unsigned char)(w & 0xffu);
}

// ---------------------------------------------------------------------------
// K0: prep — MLP weights in MFMA-fragment order.
// ---------------------------------------------------------------------------
__global__ void prep_weights(const float* __restrict__ w1, const float* __restrict__ w2,
                             const float* __restrict__ lng, const float* __restrict__ lnb,
                             const float* __restrict__ b1,
                             i64* __restrict__ W1L, i64* __restrict__ W2L,
                             float* __restrict__ B1s) {
    int i = blockIdx.x * 256 + threadIdx.x;
    if (i < 4608) {                               // W1L: 24 j16 * 3 kk * 64 lanes
        int n16 = i / 192, r = i - n16 * 192;
        int kk = r >> 6, lane = r & 63;
        int n = n16 * 16 + (lane & 15);
        int cb = kk * 32 + (lane >> 4) * 8;
        float s0 = lng[cb + 0] * w1[(cb + 0) * 384 + n];
        float s1 = lng[cb + 1] * w1[(cb + 1) * 384 + n];
        float s2 = lng[cb + 2] * w1[(cb + 2) * 384 + n];
        float s3 = lng[cb + 3] * w1[(cb + 3) * 384 + n];
        float s4 = lng[cb + 4] * w1[(cb + 4) * 384 + n];
        float s5 = lng[cb + 5] * w1[(cb + 5) * 384 + n];
        float s6 = lng[cb + 6] * w1[(cb + 6) * 384 + n];
        float s7 = lng[cb + 7] * w1[(cb + 7) * 384 + n];
        W1L[i] = mk64(pk4(s0, s1, s2, s3), pk4(s4, s5, s6, s7));
    } else if (i < 9216) {                        // W2L: 6 ct * 12 jk * 64 lanes
        int e = i - 4608;
        int r = e & 767, lane = r & 63, jk = r >> 6;
        int c = ((e / 768) * 16) + (lane & 15);
        int nb = jk * 32 + (lane >> 4) * 8;
        float s0 = w2[(nb + 0) * 96 + c], s1 = w2[(nb + 1) * 96 + c];
        float s2 = w2[(nb + 2) * 96 + c], s3 = w2[(nb + 3) * 96 + c];
        float s4 = w2[(nb + 4) * 96 + c], s5 = w2[(nb + 5) * 96 + c];
        float s6 = w2[(nb + 6) * 96 + c], s7 = w2[(nb + 7) * 96 + c];
        W2L[e] = mk64(pk4(s0, s1, s2, s3), pk4(s4, s5, s6, s7));
    } else if (i < 9600) {                        // B1s
        int n = i - 9216;
        float s = b1[n];
        for (int c = 0; c < 96; ++c) s += lnb[c] * w1[c * 384 + n];
        B1s[n] = s;
    }
}

// ---------------------------------------------------------------------------
// K0b: Toeplitz B-fragment table.
// ---------------------------------------------------------------------------
__global__ void prep_bt(const float* __restrict__ dww, unsigned char* __restrict__ BT) {
    int i = blockIdx.x * 256 + threadIdx.x;
    if (i >= 301056) return;                      // 96 * 49 * 64
    int lane = i & 63;
    int tap = (i >> 6) % 49;
    int c = i / 3136;
    int n = lane & 15, kg = lane >> 4;
    const float* wt = dww + c * 343 + tap * 7;
    float e[8];
#pragma unroll
    for (int j = 0; j < 8; ++j) {
        int t = kg * 8 + j - n;
        e[j] = (t >= 0 && t < 7) ? wt[t] : 0.f;
    }
    u32 lo = pk4(e[0], e[1], e[2], e[3]);
    u32 hi = pk4(e[4], e[5], e[6], e[7]);
    *(u32*)&BT[(size_t)i * 8] = lo;
    *(u32*)&BT[(size_t)i * 8 + 4] = hi;
}

// ---------------------------------------------------------------------------
// K1: Toeplitz fp8 MFMA conv — R13/R16 champion config (un-paired planes).
// Wave wv handles planes (wv, wv+8) sequentially. d-tile 16: LDS
// [22 pz][22 row][88 fp8] = 42.6 KB, 3 blocks/CU (62% occupancy measured).
// MERGED z=2 dispatch. fp8 conv-out (WRITE 98->49 MB).
// NOTE: adjacent-plane pairing (R14/R15) measured NET-NEGATIVE (lost a
// resident block, occ 62->44%, unexplained). Do not re-introduce.
// ---------------------------------------------------------------------------
template<int PACKED>
__global__ __launch_bounds__(512, 8) void dwconvM(const float* __restrict__ x,
                                                  const unsigned char* __restrict__ BT,
                                                  const float* __restrict__ dwb,
                                                  unsigned char* __restrict__ cw8,
                                                  u16* __restrict__ o16) {
    __shared__ __align__(16) unsigned char tile[42592];   // 22*22*88
    const int tid = threadIdx.x;
    const int bx = blockIdx.x, c = blockIdx.y, b = blockIdx.z;
    const int d0 = (bx >> 2) * 16, h0 = (bx & 3) * 16;
    const float* xc = x + ((size_t)(b * 96 + c)) * 262144;

    // ---- stage fp8 tile: 22 pz x 22 rows x 20 u32 (slot s = w+3)
    for (int i = tid; i < 9680; i += 512) {
        int pz = i / 440;
        int rem = i - pz * 440;
        int row = rem / 20;
        int u = rem - row * 20;
        int d = d0 + pz - 3, h = h0 + row - 3;
        u32 pk = 0;
        if (((unsigned)d < 64u) && ((unsigned)h < 64u)) {
            const float* xr = xc + d * 4096 + h * 64;
            if (u >= 1 && u <= 15) {               // w = 4u-3 .. 4u, all in-range
                float e[4];
                __builtin_memcpy(e, xr + 4 * u - 3, 16);
                pk = pk4(e[0], e[1], e[2], e[3]);
            } else if (u == 0) {                   // only w=0 (slot 3) valid
                pk = pk4(0.f, 0.f, 0.f, xr[0]);
            } else if (u == 16) {                  // w=61,62,63 valid
                pk = pk4(xr[61], xr[62], xr[63], 0.f);
            }                                       // u 17..19 stay zero
        }
        *(u32*)&tile[(pz * 22 + row) * 88 + u * 4] = pk;
    }
    __syncthreads();

    const int lane = tid & 63, wv = tid >> 6;
    const int n = lane & 15, g = lane >> 4;
    const unsigned char* BTl = BT + (size_t)c * 49 * 512 + (size_t)lane * 8;
    const int abase = n * 88 + 8 * g;
    const float bias = dwb[c];

#pragma unroll
    for (int plane = 0; plane < 2; ++plane) {
        const int dd = wv + plane * 8;

        f32x4 acc[4];
#pragma unroll
        for (int i = 0; i < 4; ++i) acc[i] = f32x4{0.f, 0.f, 0.f, 0.f};

        i64 bfC[7], bfN[7];
#pragma unroll
        for (int kh = 0; kh < 7; ++kh)
            bfC[kh] = *(const i64*)(BTl + (size_t)kh * 512);

#pragma unroll
        for (int kd = 0; kd < 7; ++kd) {
#pragma unroll
            for (int kh = 0; kh < 7; ++kh)
                bfN[kh] = (kd < 6) ? *(const i64*)(BTl + (size_t)((kd + 1) * 7 + kh) * 512)
                                   : (i64)0;
            const unsigned char* tb = &tile[(dd + kd) * 1936 + abase];
#pragma unroll
            for (int kh = 0; kh < 7; ++kh) {
                const unsigned char* ab = tb + kh * 88;
#pragma unroll
                for (int wt = 0; wt < 4; ++wt) {
                    i64 af = *(const i64*)(ab + 16 * wt);
                    acc[wt] = __builtin_amdgcn_mfma_f32_16x16x32_fp8_fp8(af, bfC[kh], acc[wt], 0, 0, 0);
                }
            }
#pragma unroll
            for (int kh = 0; kh < 7; ++kh) bfC[kh] = bfN[kh];
        }

        // ---- epilogue: D row m = 4g+q (h), col n (w = wt*16+n)
        const int d = d0 + dd;
#pragma unroll
        for (int wt = 0; wt < 4; ++wt) {
#pragma unroll
            for (int q = 0; q < 4; ++q) {
                int h = h0 + 4 * g + q;
                int w = wt * 16 + n;
                size_t pos = (size_t)b * 262144 + (size_t)d * 4096 + h * 64 + w;
                if (PACKED == 0)
                    cw8[(size_t)c * 524288 + pos] = f2fp8(acc[wt][q] + bias);
                else
                    o16[2 * ((size_t)(b * 96 + c) * 262144 + (size_t)d * 4096 + h * 64 + w) + 1] =
                        f2bf_rne(acc[wt][q] + bias);
            }
        }
    }
}

// ---------------------------------------------------------------------------
// K1-fallback: fp32-FMA conv (R5), used only when ws can't hold BT (PACKED=1).
// ---------------------------------------------------------------------------
template<int PACKED>
__global__ __launch_bounds__(256, 5) void dwconvA(const float* __restrict__ x,
                                                  const float* __restrict__ dww,
                                                  const float* __restrict__ dwb,
                                                  u32* cw, u16* o16) {
    __shared__ u32 tile32[7920];                  // 10 * 792
    const int tid = threadIdx.x;
    const int bx = blockIdx.x, c = blockIdx.y, b = blockIdx.z;
    const int d0 = (bx >> 2) * 4, h0 = (bx & 3) * 16;
    const float* xc = x + ((size_t)(b * 96 + c)) * 262144;

    for (int i = tid; i < 7700; i += 256) {
        int pz = i / 770;
        int rem = i - pz * 770;
        int r2 = rem / 70;
        int col = rem - r2 * 70;
        int d = d0 + pz - 3, h = h0 + 2 * r2 - 3, w = col - 3;
        float lo = 0.f, hi = 0.f;
        if (((unsigned)d < 64u) && ((unsigned)w < 64u)) {
            int base = d * 4096 + h * 64 + w;
            if ((unsigned)h < 64u) lo = xc[base];
            if ((unsigned)(h + 1) < 64u) hi = xc[base + 64];
        }
        int a = pz * 792 + r2 * 72 + col;
        int aw = ((((a >> 2) ^ ((a >> 5) & 1)) << 2)) | (a & 3);
        tile32[aw] = (u32)f2bf_rne(lo) | ((u32)f2bf_rne(hi) << 16);
    }
    __syncthreads();

    const int tx = tid & 7, ty = (tid >> 3) & 7, tz = tid >> 6;
    float a0[8], a1[8];
#pragma unroll
    for (int i = 0; i < 8; ++i) { a0[i] = 0.f; a1[i] = 0.f; }

    for (int kd = 0; kd < 7; ++kd) {
        const float* Wk = dww + c * 343 + kd * 49;
        const int pz = tz + kd;
#pragma unroll
        for (int pr = 0; pr < 4; ++pr) {
            const int g0 = pz * 198 + (ty + pr) * 18 + (tx << 1);
            u32 rb[16];
#pragma unroll
            for (int k = 0; k < 4; ++k) {
                int g = g0 + k;
                int ga = (g ^ ((g >> 3) & 1)) << 2;
                *(u32x4*)&rb[4 * k] = *(const u32x4*)(tile32 + ga);
            }
            float rlo[16], rhi[16];
#pragma unroll
            for (int t = 0; t < 16; ++t) {
                rlo[t] = __builtin_bit_cast(float, rb[t] << 16);
                rhi[t] = __builtin_bit_cast(float, rb[t]);
            }
#pragma unroll
            for (int kw = 0; kw < 7; ++kw) {
                float wA = Wk[2 * pr * 7 + kw];
#pragma unroll
                for (int i = 0; i < 8; ++i) {
                    a0[i] = fmaf(rlo[kw + i], wA, a0[i]);
                    a1[i] = fmaf(rhi[kw + i], wA, a1[i]);
                }
                if (pr < 3) {
                    float wB = Wk[(2 * pr + 1) * 7 + kw];
#pragma unroll
                    for (int i = 0; i < 8; ++i) a0[i] = fmaf(rhi[kw + i], wB, a0[i]);
                }
                if (pr > 0) {
                    float wC = Wk[(2 * pr - 1) * 7 + kw];
#pragma unroll
                    for (int i = 0; i < 8; ++i) a1[i] = fmaf(rlo[kw + i], wC, a1[i]);
                }
            }
        }
    }

    const float bias = dwb[c];
    const int d = d0 + tz;
    const int hA = h0 + 2 * ty;
    {
        size_t e = ((size_t)(b * 96 + c)) * 262144 + d * 4096 + hA * 64 + 8 * tx;
#pragma unroll
        for (int i = 0; i < 8; ++i) o16[2 * (e + i) + 1] = f2bf_rne(a0[i] + bias);
#pragma unroll
        for (int i = 0; i < 8; ++i) o16[2 * (e + 64 + i) + 1] = f2bf_rne(a1[i] + bias);
    }
    (void)cw;
}

// ---------------------------------------------------------------------------
// K2 v5: LDS-free mlp3. The per-j H redistribution (old: LDS write + lgkm
// fence + read) is a pure intra-wave exchange among the 4 G-lanes of a
// position: target (p,G), kkj needs value w[2kkj+(G>>1)] word q from lane
// p + 32(G&1) + 16q. Implemented as 8 __shfl + 4 selects per tile — no LDS,
// no fences, no barriers; blocks fully wave-independent.
// launch_bounds(256,4): VGPR must stay <=64 (cliff). If >64 -> revert to R16.
// ---------------------------------------------------------------------------
template<int CWP, int WF>
__global__ __launch_bounds__(256, 4) void mlp3(const void* cwsrc,
                                               const i64* __restrict__ W1L,
                                               const i64* __restrict__ W2L,
                                               const float* __restrict__ B1s,
                                               const float* __restrict__ w1f,
                                               const float* __restrict__ w2f,
                                               const float* __restrict__ lng,
                                               const float* __restrict__ lnb,
                                               const float* __restrict__ b1g,
                                               const float* __restrict__ b2g,
                                               const float* __restrict__ gam,
                                               const float* __restrict__ x,
                                               float* __restrict__ out) {
    const int tid = threadIdx.x;
    const int wv = tid >> 6, lane = tid & 63;
    const int p = lane & 15, G = lane >> 4;
    const int pos0 = blockIdx.x * 128 + wv * 32;
    const int b = pos0 >> 18, prel0 = pos0 & 262143;

    const int srcA = p + ((G & 1) << 5);          // lane for hF word0
    const int srcB = srcA + 16;                   // lane for hF word1
    const bool hiG = (G >> 1) != 0;               // selects w[1]/w[3] vs w[0]/w[2]

    // ---- paired gather: lane (p,G) loads one u16 = fp8 pair (pos0+2p, pos0+2p+1)
    float v0[3][8], v1[3][8];
    if (CWP == 0) {
        const u16* cwp = (const u16*)cwsrc;
#pragma unroll
        for (int kk = 0; kk < 3; ++kk)
#pragma unroll
            for (int m = 0; m < 8; ++m) {
                int c = kk * 32 + G * 8 + m;
                u16 w = cwp[(size_t)c * 262144 + (pos0 >> 1) + p];
                f32x2 pr = __builtin_amdgcn_cvt_pk_f32_fp8((int)(u32)w, false);
                v0[kk][m] = pr[0];
                v1[kk][m] = pr[1];
            }
    } else {
        const u32* ow = (const u32*)cwsrc;
#pragma unroll
        for (int kk = 0; kk < 3; ++kk)
#pragma unroll
            for (int m = 0; m < 8; ++m) {
                int c = kk * 32 + G * 8 + m;
                size_t base = ((size_t)(b * 96 + c)) * 262144 + prel0 + 2 * p;
                v0[kk][m] = bf2f((u16)(ow[base] >> 16));
                v1[kk][m] = bf2f((u16)(ow[base + 1] >> 16));
            }
    }

    // ---- LN stats for both positions (reduce across the 4 G-lanes)
    float s0 = 0.f, sq0 = 0.f, s1 = 0.f, sq1 = 0.f;
#pragma unroll
    for (int kk = 0; kk < 3; ++kk)
#pragma unroll
        for (int m = 0; m < 8; ++m) {
            s0 += v0[kk][m]; sq0 += v0[kk][m] * v0[kk][m];
            s1 += v1[kk][m]; sq1 += v1[kk][m] * v1[kk][m];
        }
    s0 += __shfl_xor(s0, 16); sq0 += __shfl_xor(sq0, 16);
    s0 += __shfl_xor(s0, 32); sq0 += __shfl_xor(sq0, 32);
    s1 += __shfl_xor(s1, 16); sq1 += __shfl_xor(sq1, 16);
    s1 += __shfl_xor(s1, 32); sq1 += __shfl_xor(sq1, 32);
    float mu0 = s0 * (1.f / 96.f);
    float rstd0 = rsqrtf(sq0 * (1.f / 96.f) - mu0 * mu0 + 1e-5f);
    float mu1 = s1 * (1.f / 96.f);
    float rstd1 = rsqrtf(sq1 * (1.f / 96.f) - mu1 * mu1 + 1e-5f);

    i64 aF[2][3];
#pragma unroll
    for (int kk = 0; kk < 3; ++kk) {
        aF[0][kk] = mk64(
            pk4((v0[kk][0] - mu0) * rstd0, (v0[kk][1] - mu0) * rstd0,
                (v0[kk][2] - mu0) * rstd0, (v0[kk][3] - mu0) * rstd0),
            pk4((v0[kk][4] - mu0) * rstd0, (v0[kk][5] - mu0) * rstd0,
                (v0[kk][6] - mu0) * rstd0, (v0[kk][7] - mu0) * rstd0));
        aF[1][kk] = mk64(
            pk4((v1[kk][0] - mu1) * rstd1, (v1[kk][1] - mu1) * rstd1,
                (v1[kk][2] - mu1) * rstd1, (v1[kk][3] - mu1) * rstd1),
            pk4((v1[kk][4] - mu1) * rstd1, (v1[kk][5] - mu1) * rstd1,
                (v1[kk][6] - mu1) * rstd1, (v1[kk][7] - mu1) * rstd1));
    }

    f32x4 acc[2][6];
#pragma unroll
    for (int t = 0; t < 2; ++t)
#pragma unroll
        for (int i = 0; i < 6; ++i) acc[t][i] = f32x4{0.f, 0.f, 0.f, 0.f};

    for (int j = 0; j < 6; ++j) {
        i64 wf[12];
#pragma unroll
        for (int q = 0; q < 12; ++q) {
            if (WF == 0) {
                wf[q] = W1L[(j * 12 + q) * 64 + lane];
            } else {
                int nt = q / 3, kk = q - nt * 3;
                int nn = (j * 4 + nt) * 16 + p;
                int cb = kk * 32 + G * 8;
                wf[q] = mk64(
                    pk4(lng[cb + 0] * w1f[(cb + 0) * 384 + nn], lng[cb + 1] * w1f[(cb + 1) * 384 + nn],
                        lng[cb + 2] * w1f[(cb + 2) * 384 + nn], lng[cb + 3] * w1f[(cb + 3) * 384 + nn]),
                    pk4(lng[cb + 4] * w1f[(cb + 4) * 384 + nn], lng[cb + 5] * w1f[(cb + 5) * 384 + nn],
                        lng[cb + 6] * w1f[(cb + 6) * 384 + nn], lng[cb + 7] * w1f[(cb + 7) * 384 + nn]));
            }
        }
        f32x4 bb[4];
#pragma unroll
        for (int nt = 0; nt < 4; ++nt)
            bb[nt] = *(const f32x4*)&B1s[(j * 4 + nt) * 16 + 4 * G];

        i64 hF[2][2];
#pragma unroll
        for (int t = 0; t < 2; ++t) {
            f32x4 c1[4];
#pragma unroll
            for (int nt = 0; nt < 4; ++nt) {
                c1[nt] = f32x4{0.f, 0.f, 0.f, 0.f};
#pragma unroll
                for (int kk = 0; kk < 3; ++kk)
                    c1[nt] = __builtin_amdgcn_mfma_f32_16x16x32_fp8_fp8(wf[nt * 3 + kk], aF[t][kk], c1[nt], 0, 0, 0);
            }
            // bias + GELU -> 4 packed fp8x4 words (nt = 0..3), statically named
            u32 w0 = pk4(gelu_fast(c1[0][0] + bb[0][0]), gelu_fast(c1[0][1] + bb[0][1]),
                         gelu_fast(c1[0][2] + bb[0][2]), gelu_fast(c1[0][3] + bb[0][3]));
            u32 w1 = pk4(gelu_fast(c1[1][0] + bb[1][0]), gelu_fast(c1[1][1] + bb[1][1]),
                         gelu_fast(c1[1][2] + bb[1][2]), gelu_fast(c1[1][3] + bb[1][3]));
            u32 w2 = pk4(gelu_fast(c1[2][0] + bb[2][0]), gelu_fast(c1[2][1] + bb[2][1]),
                         gelu_fast(c1[2][2] + bb[2][2]), gelu_fast(c1[2][3] + bb[2][3]));
            u32 w3 = pk4(gelu_fast(c1[3][0] + bb[3][0]), gelu_fast(c1[3][1] + bb[3][1]),
                         gelu_fast(c1[3][2] + bb[3][2]), gelu_fast(c1[3][3] + bb[3][3]));
            // intra-wave redistribution (replaces LDS roundtrip + fence)
            u32 a0 = (u32)__shfl((int)w0, srcA);
            u32 a1 = (u32)__shfl((int)w1, srcA);
            u32 a2 = (u32)__shfl((int)w2, srcA);
            u32 a3 = (u32)__shfl((int)w3, srcA);
            u32 b0 = (u32)__shfl((int)w0, srcB);
            u32 b1 = (u32)__shfl((int)w1, srcB);
            u32 b2 = (u32)__shfl((int)w2, srcB);
            u32 b3 = (u32)__shfl((int)w3, srcB);
            hF[t][0] = mk64(hiG ? a1 : a0, hiG ? b1 : b0);
            hF[t][1] = mk64(hiG ? a3 : a2, hiG ? b3 : b2);
        }

        i64 w2r[12];
#pragma unroll
        for (int q = 0; q < 12; ++q) {
            int ct = q >> 1, kkj = q & 1;
            if (WF == 0) {
                w2r[q] = W2L[(ct * 12 + j * 2 + kkj) * 64 + lane];
            } else {
                int cc = ct * 16 + p;
                int nb = (j * 2 + kkj) * 32 + G * 8;
                w2r[q] = mk64(
                    pk4(w2f[(nb + 0) * 96 + cc], w2f[(nb + 1) * 96 + cc],
                        w2f[(nb + 2) * 96 + cc], w2f[(nb + 3) * 96 + cc]),
                    pk4(w2f[(nb + 4) * 96 + cc], w2f[(nb + 5) * 96 + cc],
                        w2f[(nb + 6) * 96 + cc], w2f[(nb + 7) * 96 + cc]));
            }
        }

#pragma unroll
        for (int ct = 0; ct < 6; ++ct)
#pragma unroll
            for (int kkj = 0; kkj < 2; ++kkj) {
#pragma unroll
                for (int t = 0; t < 2; ++t)
                    acc[t][ct] = __builtin_amdgcn_mfma_f32_16x16x32_fp8_fp8(hF[t][kkj], w2r[ct * 2 + kkj], acc[t][ct], 0, 0, 0);
            }
    }

    // ---- epilogue: interleave tiles -> contiguous f32x4 at prel0+8G+4k
#pragma unroll
    for (int ct = 0; ct < 6; ++ct) {
        int c = ct * 16 + p;
        float b2c = b2g[c], gc = gam[c];
#pragma unroll
        for (int k = 0; k < 2; ++k) {
            size_t xi = ((size_t)(b * 96 + c)) * 262144 + prel0 + 8 * G + 4 * k;
            f32x4 xv = *(const f32x4*)&x[xi];
            f32x4 o;
            o[0] = (acc[0][ct][2 * k]     + b2c) * gc + xv[0];
            o[1] = (acc[1][ct][2 * k]     + b2c) * gc + xv[1];
            o[2] = (acc[0][ct][2 * k + 1] + b2c) * gc + xv[2];
            o[3] = (acc[1][ct][2 * k + 1] + b2c) * gc + xv[3];
            *(f32x4*)&out[xi] = o;
        }
    }
}

// ---------------------------------------------------------------------------
extern "C" void kernel_launch(void* const* d_in, const int* in_sizes, int n_in,
                              void* d_out, int out_size, void* d_ws, size_t ws_size,
                              hipStream_t stream) {
    const float* x   = (const float*)d_in[0];
    const float* dww = (const float*)d_in[1];
    const float* dwb = (const float*)d_in[2];
    const float* lng = (const float*)d_in[3];
    const float* lnb = (const float*)d_in[4];
    const float* w1  = (const float*)d_in[5];
    const float* b1  = (const float*)d_in[6];
    const float* w2  = (const float*)d_in[7];
    const float* b2  = (const float*)d_in[8];
    const float* gam = (const float*)d_in[9];
    float* out = (float*)d_out;

    // ws: W1L @0 (36864) | W2L (36864) | B1s (1536) | BT @75264 (2408448)
    //     | cw8 @2483712 (50331648 fp8)
    const size_t NEED_W  = 75264;
    const size_t NEED_BT = 75264 + 2408448ull;              // 2,483,712
    const size_t NEED_FULL = NEED_BT + 50331648ull;         // 52,815,360
    const bool wsW  = ws_size >= NEED_W;
    const bool wsBT = ws_size >= NEED_BT;
    const bool wsCW = ws_size >= NEED_FULL;

    i64* W1L = (i64*)d_ws;
    i64* W2L = (i64*)((char*)d_ws + 36864);
    float* B1s = (float*)((char*)d_ws + 73728);
    unsigned char* BT = (unsigned char*)d_ws + 75264;
    unsigned char* cw8 = (unsigned char*)d_ws + 2483712;

    if (wsW)
        hipLaunchKernelGGL(prep_weights, dim3(38), dim3(256), 0, stream,
                           w1, w2, lng, lnb, b1, W1L, W2L, B1s);
    if (wsBT)
        hipLaunchKernelGGL(prep_bt, dim3(1176), dim3(256), 0, stream, dww, BT);

    dim3 g1(16, 96, 2), blkc(512);
    if (wsCW)
        hipLaunchKernelGGL((dwconvM<0>), g1, blkc, 0, stream, x, BT, dwb, cw8, (u16*)d_out);
    else if (wsBT)
        hipLaunchKernelGGL((dwconvM<1>), g1, blkc, 0, stream, x, BT, dwb, cw8, (u16*)d_out);
    else {
        dim3 g1a(64, 96, 2), blka(256);
        hipLaunchKernelGGL((dwconvA<1>), g1a, blka, 0, stream, x, dww, dwb, (u32*)cw8, (u16*)d_out);
    }

    dim3 g2(4096), blk2(256);
    if (wsCW)
        hipLaunchKernelGGL((mlp3<0, 0>), g2, blk2, 0, stream, (const void*)cw8,
                           W1L, W2L, B1s, w1, w2, lng, lnb, b1, b2, gam, x, out);
    else if (wsW)
        hipLaunchKernelGGL((mlp3<1, 0>), g2, blk2, 0, stream, (const void*)d_out,
                           W1L, W2L, B1s, w1, w2, lng, lnb, b1, b2, gam, x, out);
    else
        hipLaunchKernelGGL((mlp3<1, 1>), g2, blk2, 0, stream, (const void*)d_out,
                           W1L, W2L, B1s, w1, w2, lng, lnb, b1, b2, gam, x, out);
}

// Round 18
// 372.441 us; speedup vs baseline: 1.0121x; 1.0121x over previous
//
#include <hip/hip_runtime.h>

typedef unsigned int u32;
typedef unsigned short u16;
typedef unsigned long long u64;
typedef long i64;
typedef float f32x4 __attribute__((ext_vector_type(4)));
typedef float f32x2 __attribute__((ext_vector_type(2)));
typedef u32 u32x4 __attribute__((ext_vector_type(4)));

__device__ __forceinline__ u16 f2bf_rne(float f) {
    return __builtin_bit_cast(u16, (__bf16)f);
}
__device__ __forceinline__ float bf2f(u16 h) {
    return __builtin_bit_cast(float, ((u32)h) << 16);
}
__device__ __forceinline__ float gelu_fast(float v) {
    float t = __builtin_amdgcn_exp2f(v * -2.4554673f);
    return v * __builtin_amdgcn_rcpf(1.f + t);
}
__device__ __forceinline__ i64 mk64(u32 lo, u32 hi) {
    return (i64)(((u64)hi << 32) | (u64)lo);
}
__device__ __forceinline__ u32 pk4(float a, float b, float c, float d) {
    u32 w = (u32)__builtin_amdgcn_cvt_pk_fp8_f32(a, b, 0, false);
    return (u32)__builtin_amdgcn_cvt_pk_fp8_f32(c, d, (int)w, true);
}
__device__ __forceinline__ unsigned char f2fp8(float a) {
    u32 w = (u32)__builtin_amdgcn_cvt_pk_fp8_f32(a, 0.f, 0, false);
    return (unsigned char)(w & 0xffu);
}

// ---------------------------------------------------------------------------
// K0: prep — MLP weights in MFMA-fragment order.
// ---------------------------------------------------------------------------
__global__ void prep_weights(const float* __restrict__ w1, const float* __restrict__ w2,
                             const float* __restrict__ lng, const float* __restrict__ lnb,
                             const float* __restrict__ b1,
                             i64* __restrict__ W1L, i64* __restrict__ W2L,
                             float* __restrict__ B1s) {
    int i = blockIdx.x * 256 + threadIdx.x;
    if (i < 4608) {                               // W1L: 24 j16 * 3 kk * 64 lanes
        int n16 = i / 192, r = i - n16 * 192;
        int kk = r >> 6, lane = r & 63;
        int n = n16 * 16 + (lane & 15);
        int cb = kk * 32 + (lane >> 4) * 8;
        float s0 = lng[cb + 0] * w1[(cb + 0) * 384 + n];
        float s1 = lng[cb + 1] * w1[(cb + 1) * 384 + n];
        float s2 = lng[cb + 2] * w1[(cb + 2) * 384 + n];
        float s3 = lng[cb + 3] * w1[(cb + 3) * 384 + n];
        float s4 = lng[cb + 4] * w1[(cb + 4) * 384 + n];
        float s5 = lng[cb + 5] * w1[(cb + 5) * 384 + n];
        float s6 = lng[cb + 6] * w1[(cb + 6) * 384 + n];
        float s7 = lng[cb + 7] * w1[(cb + 7) * 384 + n];
        W1L[i] = mk64(pk4(s0, s1, s2, s3), pk4(s4, s5, s6, s7));
    } else if (i < 9216) {                        // W2L: 6 ct * 12 jk * 64 lanes
        int e = i - 4608;
        int r = e & 767, lane = r & 63, jk = r >> 6;
        int c = ((e / 768) * 16) + (lane & 15);
        int nb = jk * 32 + (lane >> 4) * 8;
        float s0 = w2[(nb + 0) * 96 + c], s1 = w2[(nb + 1) * 96 + c];
        float s2 = w2[(nb + 2) * 96 + c], s3 = w2[(nb + 3) * 96 + c];
        float s4 = w2[(nb + 4) * 96 + c], s5 = w2[(nb + 5) * 96 + c];
        float s6 = w2[(nb + 6) * 96 + c], s7 = w2[(nb + 7) * 96 + c];
        W2L[e] = mk64(pk4(s0, s1, s2, s3), pk4(s4, s5, s6, s7));
    } else if (i < 9600) {                        // B1s
        int n = i - 9216;
        float s = b1[n];
        for (int c = 0; c < 96; ++c) s += lnb[c] * w1[c * 384 + n];
        B1s[n] = s;
    }
}

// ---------------------------------------------------------------------------
// K0b: Toeplitz B-fragment table.
// ---------------------------------------------------------------------------
__global__ void prep_bt(const float* __restrict__ dww, unsigned char* __restrict__ BT) {
    int i = blockIdx.x * 256 + threadIdx.x;
    if (i >= 301056) return;                      // 96 * 49 * 64
    int lane = i & 63;
    int tap = (i >> 6) % 49;
    int c = i / 3136;
    int n = lane & 15, kg = lane >> 4;
    const float* wt = dww + c * 343 + tap * 7;
    float e[8];
#pragma unroll
    for (int j = 0; j < 8; ++j) {
        int t = kg * 8 + j - n;
        e[j] = (t >= 0 && t < 7) ? wt[t] : 0.f;
    }
    u32 lo = pk4(e[0], e[1], e[2], e[3]);
    u32 hi = pk4(e[4], e[5], e[6], e[7]);
    *(u32*)&BT[(size_t)i * 8] = lo;
    *(u32*)&BT[(size_t)i * 8 + 4] = hi;
}

// ---------------------------------------------------------------------------
// K1: Toeplitz fp8 MFMA conv — champion config (R13/R16).
// Wave wv handles planes (wv, wv+8) sequentially. d-tile 16: LDS
// [22 pz][22 row][88 fp8] = 42.6 KB, 3 blocks/CU (62% occupancy measured).
// MERGED z=2 dispatch. fp8 conv-out (WRITE 98->49 MB).
// Tried and rejected: adjacent-plane pairing (R14/R15, lost a resident
// block), split per-batch dispatch (R12, double tail-drain).
// ---------------------------------------------------------------------------
template<int PACKED>
__global__ __launch_bounds__(512, 8) void dwconvM(const float* __restrict__ x,
                                                  const unsigned char* __restrict__ BT,
                                                  const float* __restrict__ dwb,
                                                  unsigned char* __restrict__ cw8,
                                                  u16* __restrict__ o16) {
    __shared__ __align__(16) unsigned char tile[42592];   // 22*22*88
    const int tid = threadIdx.x;
    const int bx = blockIdx.x, c = blockIdx.y, b = blockIdx.z;
    const int d0 = (bx >> 2) * 16, h0 = (bx & 3) * 16;
    const float* xc = x + ((size_t)(b * 96 + c)) * 262144;

    // ---- stage fp8 tile: 22 pz x 22 rows x 20 u32 (slot s = w+3)
    for (int i = tid; i < 9680; i += 512) {
        int pz = i / 440;
        int rem = i - pz * 440;
        int row = rem / 20;
        int u = rem - row * 20;
        int d = d0 + pz - 3, h = h0 + row - 3;
        u32 pk = 0;
        if (((unsigned)d < 64u) && ((unsigned)h < 64u)) {
            const float* xr = xc + d * 4096 + h * 64;
            if (u >= 1 && u <= 15) {               // w = 4u-3 .. 4u, all in-range
                float e[4];
                __builtin_memcpy(e, xr + 4 * u - 3, 16);
                pk = pk4(e[0], e[1], e[2], e[3]);
            } else if (u == 0) {                   // only w=0 (slot 3) valid
                pk = pk4(0.f, 0.f, 0.f, xr[0]);
            } else if (u == 16) {                  // w=61,62,63 valid
                pk = pk4(xr[61], xr[62], xr[63], 0.f);
            }                                       // u 17..19 stay zero
        }
        *(u32*)&tile[(pz * 22 + row) * 88 + u * 4] = pk;
    }
    __syncthreads();

    const int lane = tid & 63, wv = tid >> 6;
    const int n = lane & 15, g = lane >> 4;
    const unsigned char* BTl = BT + (size_t)c * 49 * 512 + (size_t)lane * 8;
    const int abase = n * 88 + 8 * g;
    const float bias = dwb[c];

#pragma unroll
    for (int plane = 0; plane < 2; ++plane) {
        const int dd = wv + plane * 8;

        f32x4 acc[4];
#pragma unroll
        for (int i = 0; i < 4; ++i) acc[i] = f32x4{0.f, 0.f, 0.f, 0.f};

        i64 bfC[7], bfN[7];
#pragma unroll
        for (int kh = 0; kh < 7; ++kh)
            bfC[kh] = *(const i64*)(BTl + (size_t)kh * 512);

#pragma unroll
        for (int kd = 0; kd < 7; ++kd) {
#pragma unroll
            for (int kh = 0; kh < 7; ++kh)
                bfN[kh] = (kd < 6) ? *(const i64*)(BTl + (size_t)((kd + 1) * 7 + kh) * 512)
                                   : (i64)0;
            const unsigned char* tb = &tile[(dd + kd) * 1936 + abase];
#pragma unroll
            for (int kh = 0; kh < 7; ++kh) {
                const unsigned char* ab = tb + kh * 88;
#pragma unroll
                for (int wt = 0; wt < 4; ++wt) {
                    i64 af = *(const i64*)(ab + 16 * wt);
                    acc[wt] = __builtin_amdgcn_mfma_f32_16x16x32_fp8_fp8(af, bfC[kh], acc[wt], 0, 0, 0);
                }
            }
#pragma unroll
            for (int kh = 0; kh < 7; ++kh) bfC[kh] = bfN[kh];
        }

        // ---- epilogue: D row m = 4g+q (h), col n (w = wt*16+n)
        const int d = d0 + dd;
#pragma unroll
        for (int wt = 0; wt < 4; ++wt) {
#pragma unroll
            for (int q = 0; q < 4; ++q) {
                int h = h0 + 4 * g + q;
                int w = wt * 16 + n;
                size_t pos = (size_t)b * 262144 + (size_t)d * 4096 + h * 64 + w;
                if (PACKED == 0)
                    cw8[(size_t)c * 524288 + pos] = f2fp8(acc[wt][q] + bias);
                else
                    o16[2 * ((size_t)(b * 96 + c) * 262144 + (size_t)d * 4096 + h * 64 + w) + 1] =
                        f2bf_rne(acc[wt][q] + bias);
            }
        }
    }
}

// ---------------------------------------------------------------------------
// K1-fallback: fp32-FMA conv (R5), used only when ws can't hold BT (PACKED=1).
// ---------------------------------------------------------------------------
template<int PACKED>
__global__ __launch_bounds__(256, 5) void dwconvA(const float* __restrict__ x,
                                                  const float* __restrict__ dww,
                                                  const float* __restrict__ dwb,
                                                  u32* cw, u16* o16) {
    __shared__ u32 tile32[7920];                  // 10 * 792
    const int tid = threadIdx.x;
    const int bx = blockIdx.x, c = blockIdx.y, b = blockIdx.z;
    const int d0 = (bx >> 2) * 4, h0 = (bx & 3) * 16;
    const float* xc = x + ((size_t)(b * 96 + c)) * 262144;

    for (int i = tid; i < 7700; i += 256) {
        int pz = i / 770;
        int rem = i - pz * 770;
        int r2 = rem / 70;
        int col = rem - r2 * 70;
        int d = d0 + pz - 3, h = h0 + 2 * r2 - 3, w = col - 3;
        float lo = 0.f, hi = 0.f;
        if (((unsigned)d < 64u) && ((unsigned)w < 64u)) {
            int base = d * 4096 + h * 64 + w;
            if ((unsigned)h < 64u) lo = xc[base];
            if ((unsigned)(h + 1) < 64u) hi = xc[base + 64];
        }
        int a = pz * 792 + r2 * 72 + col;
        int aw = ((((a >> 2) ^ ((a >> 5) & 1)) << 2)) | (a & 3);
        tile32[aw] = (u32)f2bf_rne(lo) | ((u32)f2bf_rne(hi) << 16);
    }
    __syncthreads();

    const int tx = tid & 7, ty = (tid >> 3) & 7, tz = tid >> 6;
    float a0[8], a1[8];
#pragma unroll
    for (int i = 0; i < 8; ++i) { a0[i] = 0.f; a1[i] = 0.f; }

    for (int kd = 0; kd < 7; ++kd) {
        const float* Wk = dww + c * 343 + kd * 49;
        const int pz = tz + kd;
#pragma unroll
        for (int pr = 0; pr < 4; ++pr) {
            const int g0 = pz * 198 + (ty + pr) * 18 + (tx << 1);
            u32 rb[16];
#pragma unroll
            for (int k = 0; k < 4; ++k) {
                int g = g0 + k;
                int ga = (g ^ ((g >> 3) & 1)) << 2;
                *(u32x4*)&rb[4 * k] = *(const u32x4*)(tile32 + ga);
            }
            float rlo[16], rhi[16];
#pragma unroll
            for (int t = 0; t < 16; ++t) {
                rlo[t] = __builtin_bit_cast(float, rb[t] << 16);
                rhi[t] = __builtin_bit_cast(float, rb[t]);
            }
#pragma unroll
            for (int kw = 0; kw < 7; ++kw) {
                float wA = Wk[2 * pr * 7 + kw];
#pragma unroll
                for (int i = 0; i < 8; ++i) {
                    a0[i] = fmaf(rlo[kw + i], wA, a0[i]);
                    a1[i] = fmaf(rhi[kw + i], wA, a1[i]);
                }
                if (pr < 3) {
                    float wB = Wk[(2 * pr + 1) * 7 + kw];
#pragma unroll
                    for (int i = 0; i < 8; ++i) a0[i] = fmaf(rhi[kw + i], wB, a0[i]);
                }
                if (pr > 0) {
                    float wC = Wk[(2 * pr - 1) * 7 + kw];
#pragma unroll
                    for (int i = 0; i < 8; ++i) a1[i] = fmaf(rlo[kw + i], wC, a1[i]);
                }
            }
        }
    }

    const float bias = dwb[c];
    const int d = d0 + tz;
    const int hA = h0 + 2 * ty;
    {
        size_t e = ((size_t)(b * 96 + c)) * 262144 + d * 4096 + hA * 64 + 8 * tx;
#pragma unroll
        for (int i = 0; i < 8; ++i) o16[2 * (e + i) + 1] = f2bf_rne(a0[i] + bias);
#pragma unroll
        for (int i = 0; i < 8; ++i) o16[2 * (e + 64 + i) + 1] = f2bf_rne(a1[i] + bias);
    }
    (void)cw;
}

// ---------------------------------------------------------------------------
// K2 v4 (champion): paired-position gather from FP8 cw + per-wave LDS H
// scratch + interleaved f32x4 epilogue. The R17 shuffle variant (LDS-free)
// measured +8 us — the LDS round-trip latency is hidden by TLP while shuffles
// add VALU on the GEMM1->GEMM2 critical path. Keep the LDS version.
// launch_bounds(256,4): VGPR must stay <=64 (cliff at 65).
// ---------------------------------------------------------------------------
template<int CWP, int WF>
__global__ __launch_bounds__(256, 4) void mlp3(const void* cwsrc,
                                               const i64* __restrict__ W1L,
                                               const i64* __restrict__ W2L,
                                               const float* __restrict__ B1s,
                                               const float* __restrict__ w1f,
                                               const float* __restrict__ w2f,
                                               const float* __restrict__ lng,
                                               const float* __restrict__ lnb,
                                               const float* __restrict__ b1g,
                                               const float* __restrict__ b2g,
                                               const float* __restrict__ gam,
                                               const float* __restrict__ x,
                                               float* __restrict__ out) {
    __shared__ __align__(16) unsigned char HS[4][2][1152];  // [wave][tile][16 slots * 72B]

    const int tid = threadIdx.x;
    const int wv = tid >> 6, lane = tid & 63;
    const int p = lane & 15, G = lane >> 4;
    const int pos0 = blockIdx.x * 128 + wv * 32;
    const int b = pos0 >> 18, prel0 = pos0 & 262143;
    unsigned char* hsw = &HS[wv][0][0];

    // ---- paired gather: lane (p,G) loads one u16 = fp8 pair (pos0+2p, pos0+2p+1)
    float v0[3][8], v1[3][8];
    if (CWP == 0) {
        const u16* cwp = (const u16*)cwsrc;
#pragma unroll
        for (int kk = 0; kk < 3; ++kk)
#pragma unroll
            for (int m = 0; m < 8; ++m) {
                int c = kk * 32 + G * 8 + m;
                u16 w = cwp[(size_t)c * 262144 + (pos0 >> 1) + p];
                f32x2 pr = __builtin_amdgcn_cvt_pk_f32_fp8((int)(u32)w, false);
                v0[kk][m] = pr[0];
                v1[kk][m] = pr[1];
            }
    } else {
        const u32* ow = (const u32*)cwsrc;
#pragma unroll
        for (int kk = 0; kk < 3; ++kk)
#pragma unroll
            for (int m = 0; m < 8; ++m) {
                int c = kk * 32 + G * 8 + m;
                size_t base = ((size_t)(b * 96 + c)) * 262144 + prel0 + 2 * p;
                v0[kk][m] = bf2f((u16)(ow[base] >> 16));
                v1[kk][m] = bf2f((u16)(ow[base + 1] >> 16));
            }
    }

    // ---- LN stats for both positions (reduce across the 4 G-lanes)
    float s0 = 0.f, sq0 = 0.f, s1 = 0.f, sq1 = 0.f;
#pragma unroll
    for (int kk = 0; kk < 3; ++kk)
#pragma unroll
        for (int m = 0; m < 8; ++m) {
            s0 += v0[kk][m]; sq0 += v0[kk][m] * v0[kk][m];
            s1 += v1[kk][m]; sq1 += v1[kk][m] * v1[kk][m];
        }
    s0 += __shfl_xor(s0, 16); sq0 += __shfl_xor(sq0, 16);
    s0 += __shfl_xor(s0, 32); sq0 += __shfl_xor(sq0, 32);
    s1 += __shfl_xor(s1, 16); sq1 += __shfl_xor(sq1, 16);
    s1 += __shfl_xor(s1, 32); sq1 += __shfl_xor(sq1, 32);
    float mu0 = s0 * (1.f / 96.f);
    float rstd0 = rsqrtf(sq0 * (1.f / 96.f) - mu0 * mu0 + 1e-5f);
    float mu1 = s1 * (1.f / 96.f);
    float rstd1 = rsqrtf(sq1 * (1.f / 96.f) - mu1 * mu1 + 1e-5f);

    i64 aF[2][3];
#pragma unroll
    for (int kk = 0; kk < 3; ++kk) {
        aF[0][kk] = mk64(
            pk4((v0[kk][0] - mu0) * rstd0, (v0[kk][1] - mu0) * rstd0,
                (v0[kk][2] - mu0) * rstd0, (v0[kk][3] - mu0) * rstd0),
            pk4((v0[kk][4] - mu0) * rstd0, (v0[kk][5] - mu0) * rstd0,
                (v0[kk][6] - mu0) * rstd0, (v0[kk][7] - mu0) * rstd0));
        aF[1][kk] = mk64(
            pk4((v1[kk][0] - mu1) * rstd1, (v1[kk][1] - mu1) * rstd1,
                (v1[kk][2] - mu1) * rstd1, (v1[kk][3] - mu1) * rstd1),
            pk4((v1[kk][4] - mu1) * rstd1, (v1[kk][5] - mu1) * rstd1,
                (v1[kk][6] - mu1) * rstd1, (v1[kk][7] - mu1) * rstd1));
    }

    f32x4 acc[2][6];
#pragma unroll
    for (int t = 0; t < 2; ++t)
#pragma unroll
        for (int i = 0; i < 6; ++i) acc[t][i] = f32x4{0.f, 0.f, 0.f, 0.f};

    for (int j = 0; j < 6; ++j) {
        i64 wf[12];
#pragma unroll
        for (int q = 0; q < 12; ++q) {
            if (WF == 0) {
                wf[q] = W1L[(j * 12 + q) * 64 + lane];
            } else {
                int nt = q / 3, kk = q - nt * 3;
                int nn = (j * 4 + nt) * 16 + p;
                int cb = kk * 32 + G * 8;
                wf[q] = mk64(
                    pk4(lng[cb + 0] * w1f[(cb + 0) * 384 + nn], lng[cb + 1] * w1f[(cb + 1) * 384 + nn],
                        lng[cb + 2] * w1f[(cb + 2) * 384 + nn], lng[cb + 3] * w1f[(cb + 3) * 384 + nn]),
                    pk4(lng[cb + 4] * w1f[(cb + 4) * 384 + nn], lng[cb + 5] * w1f[(cb + 5) * 384 + nn],
                        lng[cb + 6] * w1f[(cb + 6) * 384 + nn], lng[cb + 7] * w1f[(cb + 7) * 384 + nn]));
            }
        }
        f32x4 bb[4];
#pragma unroll
        for (int nt = 0; nt < 4; ++nt)
            bb[nt] = *(const f32x4*)&B1s[(j * 4 + nt) * 16 + 4 * G];

#pragma unroll
        for (int t = 0; t < 2; ++t) {
            f32x4 c1[4];
#pragma unroll
            for (int nt = 0; nt < 4; ++nt) {
                c1[nt] = f32x4{0.f, 0.f, 0.f, 0.f};
#pragma unroll
                for (int kk = 0; kk < 3; ++kk)
                    c1[nt] = __builtin_amdgcn_mfma_f32_16x16x32_fp8_fp8(wf[nt * 3 + kk], aF[t][kk], c1[nt], 0, 0, 0);
            }
#pragma unroll
            for (int nt = 0; nt < 4; ++nt) {
                float g0 = gelu_fast(c1[nt][0] + bb[nt][0]);
                float g1 = gelu_fast(c1[nt][1] + bb[nt][1]);
                float g2 = gelu_fast(c1[nt][2] + bb[nt][2]);
                float g3 = gelu_fast(c1[nt][3] + bb[nt][3]);
                *(u32*)&hsw[t * 1152 + p * 72 + nt * 16 + 4 * G] = pk4(g0, g1, g2, g3);
            }
        }

        i64 w2r[12];
#pragma unroll
        for (int q = 0; q < 12; ++q) {
            int ct = q >> 1, kkj = q & 1;
            if (WF == 0) {
                w2r[q] = W2L[(ct * 12 + j * 2 + kkj) * 64 + lane];
            } else {
                int cc = ct * 16 + p;
                int nb = (j * 2 + kkj) * 32 + G * 8;
                w2r[q] = mk64(
                    pk4(w2f[(nb + 0) * 96 + cc], w2f[(nb + 1) * 96 + cc],
                        w2f[(nb + 2) * 96 + cc], w2f[(nb + 3) * 96 + cc]),
                    pk4(w2f[(nb + 4) * 96 + cc], w2f[(nb + 5) * 96 + cc],
                        w2f[(nb + 6) * 96 + cc], w2f[(nb + 7) * 96 + cc]));
            }
        }

        asm volatile("s_waitcnt lgkmcnt(0)" ::: "memory");
        __builtin_amdgcn_sched_barrier(0);

        i64 hF[2][2];
#pragma unroll
        for (int t = 0; t < 2; ++t)
#pragma unroll
            for (int kkj = 0; kkj < 2; ++kkj)
                hF[t][kkj] = *(const i64*)&hsw[t * 1152 + p * 72 + kkj * 32 + G * 8];

#pragma unroll
        for (int ct = 0; ct < 6; ++ct)
#pragma unroll
            for (int kkj = 0; kkj < 2; ++kkj) {
#pragma unroll
                for (int t = 0; t < 2; ++t)
                    acc[t][ct] = __builtin_amdgcn_mfma_f32_16x16x32_fp8_fp8(hF[t][kkj], w2r[ct * 2 + kkj], acc[t][ct], 0, 0, 0);
            }
    }

    // ---- epilogue: interleave tiles -> contiguous f32x4 at prel0+8G+4k
#pragma unroll
    for (int ct = 0; ct < 6; ++ct) {
        int c = ct * 16 + p;
        float b2c = b2g[c], gc = gam[c];
#pragma unroll
        for (int k = 0; k < 2; ++k) {
            size_t xi = ((size_t)(b * 96 + c)) * 262144 + prel0 + 8 * G + 4 * k;
            f32x4 xv = *(const f32x4*)&x[xi];
            f32x4 o;
            o[0] = (acc[0][ct][2 * k]     + b2c) * gc + xv[0];
            o[1] = (acc[1][ct][2 * k]     + b2c) * gc + xv[1];
            o[2] = (acc[0][ct][2 * k + 1] + b2c) * gc + xv[2];
            o[3] = (acc[1][ct][2 * k + 1] + b2c) * gc + xv[3];
            *(f32x4*)&out[xi] = o;
        }
    }
}

// ---------------------------------------------------------------------------
extern "C" void kernel_launch(void* const* d_in, const int* in_sizes, int n_in,
                              void* d_out, int out_size, void* d_ws, size_t ws_size,
                              hipStream_t stream) {
    const float* x   = (const float*)d_in[0];
    const float* dww = (const float*)d_in[1];
    const float* dwb = (const float*)d_in[2];
    const float* lng = (const float*)d_in[3];
    const float* lnb = (const float*)d_in[4];
    const float* w1  = (const float*)d_in[5];
    const float* b1  = (const float*)d_in[6];
    const float* w2  = (const float*)d_in[7];
    const float* b2  = (const float*)d_in[8];
    const float* gam = (const float*)d_in[9];
    float* out = (float*)d_out;

    // ws: W1L @0 (36864) | W2L (36864) | B1s (1536) | BT @75264 (2408448)
    //     | cw8 @2483712 (50331648 fp8)
    const size_t NEED_W  = 75264;
    const size_t NEED_BT = 75264 + 2408448ull;              // 2,483,712
    const size_t NEED_FULL = NEED_BT + 50331648ull;         // 52,815,360
    const bool wsW  = ws_size >= NEED_W;
    const bool wsBT = ws_size >= NEED_BT;
    const bool wsCW = ws_size >= NEED_FULL;

    i64* W1L = (i64*)d_ws;
    i64* W2L = (i64*)((char*)d_ws + 36864);
    float* B1s = (float*)((char*)d_ws + 73728);
    unsigned char* BT = (unsigned char*)d_ws + 75264;
    unsigned char* cw8 = (unsigned char*)d_ws + 2483712;

    if (wsW)
        hipLaunchKernelGGL(prep_weights, dim3(38), dim3(256), 0, stream,
                           w1, w2, lng, lnb, b1, W1L, W2L, B1s);
    if (wsBT)
        hipLaunchKernelGGL(prep_bt, dim3(1176), dim3(256), 0, stream, dww, BT);

    dim3 g1(16, 96, 2), blkc(512);
    if (wsCW)
        hipLaunchKernelGGL((dwconvM<0>), g1, blkc, 0, stream, x, BT, dwb, cw8, (u16*)d_out);
    else if (wsBT)
        hipLaunchKernelGGL((dwconvM<1>), g1, blkc, 0, stream, x, BT, dwb, cw8, (u16*)d_out);
    else {
        dim3 g1a(64, 96, 2), blka(256);
        hipLaunchKernelGGL((dwconvA<1>), g1a, blka, 0, stream, x, dww, dwb, (u32*)cw8, (u16*)d_out);
    }

    dim3 g2(4096), blk2(256);
    if (wsCW)
        hipLaunchKernelGGL((mlp3<0, 0>), g2, blk2, 0, stream, (const void*)cw8,
                           W1L, W2L, B1s, w1, w2, lng, lnb, b1, b2, gam, x, out);
    else if (wsW)
        hipLaunchKernelGGL((mlp3<1, 0>), g2, blk2, 0, stream, (const void*)d_out,
                           W1L, W2L, B1s, w1, w2, lng, lnb, b1, b2, gam, x, out);
    else
        hipLaunchKernelGGL((mlp3<1, 1>), g2, blk2, 0, stream, (const void*)d_out,
                           W1L, W2L, B1s, w1, w2, lng, lnb, b1, b2, gam, x, out);
}

// Round 19
// 371.034 us; speedup vs baseline: 1.0159x; 1.0038x over previous
//
#include <hip/hip_runtime.h>

typedef unsigned int u32;
typedef unsigned short u16;
typedef unsigned long long u64;
typedef long i64;
typedef float f32x4 __attribute__((ext_vector_type(4)));
typedef float f32x2 __attribute__((ext_vector_type(2)));
typedef u32 u32x4 __attribute__((ext_vector_type(4)));

__device__ __forceinline__ u16 f2bf_rne(float f) {
    return __builtin_bit_cast(u16, (__bf16)f);
}
__device__ __forceinline__ float bf2f(u16 h) {
    return __builtin_bit_cast(float, ((u32)h) << 16);
}
__device__ __forceinline__ float gelu_fast(float v) {
    float t = __builtin_amdgcn_exp2f(v * -2.4554673f);
    return v * __builtin_amdgcn_rcpf(1.f + t);
}
__device__ __forceinline__ i64 mk64(u32 lo, u32 hi) {
    return (i64)(((u64)hi << 32) | (u64)lo);
}
__device__ __forceinline__ u32 pk4(float a, float b, float c, float d) {
    u32 w = (u32)__builtin_amdgcn_cvt_pk_fp8_f32(a, b, 0, false);
    return (u32)__builtin_amdgcn_cvt_pk_fp8_f32(c, d, (int)w, true);
}
__device__ __forceinline__ unsigned char f2fp8(float a) {
    u32 w = (u32)__builtin_amdgcn_cvt_pk_fp8_f32(a, 0.f, 0, false);
    return (unsigned char)(w & 0xffu);
}

// ---------------------------------------------------------------------------
// K0: prep — MLP weights in MFMA-fragment order.
// ---------------------------------------------------------------------------
__global__ void prep_weights(const float* __restrict__ w1, const float* __restrict__ w2,
                             const float* __restrict__ lng, const float* __restrict__ lnb,
                             const float* __restrict__ b1,
                             i64* __restrict__ W1L, i64* __restrict__ W2L,
                             float* __restrict__ B1s) {
    int i = blockIdx.x * 256 + threadIdx.x;
    if (i < 4608) {                               // W1L: 24 j16 * 3 kk * 64 lanes
        int n16 = i / 192, r = i - n16 * 192;
        int kk = r >> 6, lane = r & 63;
        int n = n16 * 16 + (lane & 15);
        int cb = kk * 32 + (lane >> 4) * 8;
        float s0 = lng[cb + 0] * w1[(cb + 0) * 384 + n];
        float s1 = lng[cb + 1] * w1[(cb + 1) * 384 + n];
        float s2 = lng[cb + 2] * w1[(cb + 2) * 384 + n];
        float s3 = lng[cb + 3] * w1[(cb + 3) * 384 + n];
        float s4 = lng[cb + 4] * w1[(cb + 4) * 384 + n];
        float s5 = lng[cb + 5] * w1[(cb + 5) * 384 + n];
        float s6 = lng[cb + 6] * w1[(cb + 6) * 384 + n];
        float s7 = lng[cb + 7] * w1[(cb + 7) * 384 + n];
        W1L[i] = mk64(pk4(s0, s1, s2, s3), pk4(s4, s5, s6, s7));
    } else if (i < 9216) {                        // W2L: 6 ct * 12 jk * 64 lanes
        int e = i - 4608;
        int r = e & 767, lane = r & 63, jk = r >> 6;
        int c = ((e / 768) * 16) + (lane & 15);
        int nb = jk * 32 + (lane >> 4) * 8;
        float s0 = w2[(nb + 0) * 96 + c], s1 = w2[(nb + 1) * 96 + c];
        float s2 = w2[(nb + 2) * 96 + c], s3 = w2[(nb + 3) * 96 + c];
        float s4 = w2[(nb + 4) * 96 + c], s5 = w2[(nb + 5) * 96 + c];
        float s6 = w2[(nb + 6) * 96 + c], s7 = w2[(nb + 7) * 96 + c];
        W2L[e] = mk64(pk4(s0, s1, s2, s3), pk4(s4, s5, s6, s7));
    } else if (i < 9600) {                        // B1s
        int n = i - 9216;
        float s = b1[n];
        for (int c = 0; c < 96; ++c) s += lnb[c] * w1[c * 384 + n];
        B1s[n] = s;
    }
}

// ---------------------------------------------------------------------------
// K0b: Toeplitz B-fragment table.
// ---------------------------------------------------------------------------
__global__ void prep_bt(const float* __restrict__ dww, unsigned char* __restrict__ BT) {
    int i = blockIdx.x * 256 + threadIdx.x;
    if (i >= 301056) return;                      // 96 * 49 * 64
    int lane = i & 63;
    int tap = (i >> 6) % 49;
    int c = i / 3136;
    int n = lane & 15, kg = lane >> 4;
    const float* wt = dww + c * 343 + tap * 7;
    float e[8];
#pragma unroll
    for (int j = 0; j < 8; ++j) {
        int t = kg * 8 + j - n;
        e[j] = (t >= 0 && t < 7) ? wt[t] : 0.f;
    }
    u32 lo = pk4(e[0], e[1], e[2], e[3]);
    u32 hi = pk4(e[4], e[5], e[6], e[7]);
    *(u32*)&BT[(size_t)i * 8] = lo;
    *(u32*)&BT[(size_t)i * 8 + 4] = hi;
}

// ---------------------------------------------------------------------------
// K1: Toeplitz fp8 MFMA conv — champion config + T5 setprio around the MFMA
// cluster. 3 independent blocks/CU at staggered stage/compute phases ->
// setprio(1) lets MFMA-phase waves win issue arbitration vs staging waves.
// ---------------------------------------------------------------------------
template<int PACKED>
__global__ __launch_bounds__(512, 8) void dwconvM(const float* __restrict__ x,
                                                  const unsigned char* __restrict__ BT,
                                                  const float* __restrict__ dwb,
                                                  unsigned char* __restrict__ cw8,
                                                  u16* __restrict__ o16) {
    __shared__ __align__(16) unsigned char tile[42592];   // 22*22*88
    const int tid = threadIdx.x;
    const int bx = blockIdx.x, c = blockIdx.y, b = blockIdx.z;
    const int d0 = (bx >> 2) * 16, h0 = (bx & 3) * 16;
    const float* xc = x + ((size_t)(b * 96 + c)) * 262144;

    // ---- stage fp8 tile: 22 pz x 22 rows x 20 u32 (slot s = w+3)
    for (int i = tid; i < 9680; i += 512) {
        int pz = i / 440;
        int rem = i - pz * 440;
        int row = rem / 20;
        int u = rem - row * 20;
        int d = d0 + pz - 3, h = h0 + row - 3;
        u32 pk = 0;
        if (((unsigned)d < 64u) && ((unsigned)h < 64u)) {
            const float* xr = xc + d * 4096 + h * 64;
            if (u >= 1 && u <= 15) {               // w = 4u-3 .. 4u, all in-range
                float e[4];
                __builtin_memcpy(e, xr + 4 * u - 3, 16);
                pk = pk4(e[0], e[1], e[2], e[3]);
            } else if (u == 0) {                   // only w=0 (slot 3) valid
                pk = pk4(0.f, 0.f, 0.f, xr[0]);
            } else if (u == 16) {                  // w=61,62,63 valid
                pk = pk4(xr[61], xr[62], xr[63], 0.f);
            }                                       // u 17..19 stay zero
        }
        *(u32*)&tile[(pz * 22 + row) * 88 + u * 4] = pk;
    }
    __syncthreads();

    const int lane = tid & 63, wv = tid >> 6;
    const int n = lane & 15, g = lane >> 4;
    const unsigned char* BTl = BT + (size_t)c * 49 * 512 + (size_t)lane * 8;
    const int abase = n * 88 + 8 * g;
    const float bias = dwb[c];

#pragma unroll
    for (int plane = 0; plane < 2; ++plane) {
        const int dd = wv + plane * 8;

        f32x4 acc[4];
#pragma unroll
        for (int i = 0; i < 4; ++i) acc[i] = f32x4{0.f, 0.f, 0.f, 0.f};

        i64 bfC[7], bfN[7];
#pragma unroll
        for (int kh = 0; kh < 7; ++kh)
            bfC[kh] = *(const i64*)(BTl + (size_t)kh * 512);

#pragma unroll
        for (int kd = 0; kd < 7; ++kd) {
            // BT prefetch for kd+1 at normal priority
#pragma unroll
            for (int kh = 0; kh < 7; ++kh)
                bfN[kh] = (kd < 6) ? *(const i64*)(BTl + (size_t)((kd + 1) * 7 + kh) * 512)
                                   : (i64)0;
            const unsigned char* tb = &tile[(dd + kd) * 1936 + abase];
            __builtin_amdgcn_s_setprio(1);         // T5: favor MFMA-phase waves
#pragma unroll
            for (int kh = 0; kh < 7; ++kh) {
                const unsigned char* ab = tb + kh * 88;
#pragma unroll
                for (int wt = 0; wt < 4; ++wt) {
                    i64 af = *(const i64*)(ab + 16 * wt);
                    acc[wt] = __builtin_amdgcn_mfma_f32_16x16x32_fp8_fp8(af, bfC[kh], acc[wt], 0, 0, 0);
                }
            }
            __builtin_amdgcn_s_setprio(0);
#pragma unroll
            for (int kh = 0; kh < 7; ++kh) bfC[kh] = bfN[kh];
        }

        // ---- epilogue: D row m = 4g+q (h), col n (w = wt*16+n)
        const int d = d0 + dd;
#pragma unroll
        for (int wt = 0; wt < 4; ++wt) {
#pragma unroll
            for (int q = 0; q < 4; ++q) {
                int h = h0 + 4 * g + q;
                int w = wt * 16 + n;
                size_t pos = (size_t)b * 262144 + (size_t)d * 4096 + h * 64 + w;
                if (PACKED == 0)
                    cw8[(size_t)c * 524288 + pos] = f2fp8(acc[wt][q] + bias);
                else
                    o16[2 * ((size_t)(b * 96 + c) * 262144 + (size_t)d * 4096 + h * 64 + w) + 1] =
                        f2bf_rne(acc[wt][q] + bias);
            }
        }
    }
}

// ---------------------------------------------------------------------------
// K1-fallback: fp32-FMA conv (R5), used only when ws can't hold BT (PACKED=1).
// ---------------------------------------------------------------------------
template<int PACKED>
__global__ __launch_bounds__(256, 5) void dwconvA(const float* __restrict__ x,
                                                  const float* __restrict__ dww,
                                                  const float* __restrict__ dwb,
                                                  u32* cw, u16* o16) {
    __shared__ u32 tile32[7920];                  // 10 * 792
    const int tid = threadIdx.x;
    const int bx = blockIdx.x, c = blockIdx.y, b = blockIdx.z;
    const int d0 = (bx >> 2) * 4, h0 = (bx & 3) * 16;
    const float* xc = x + ((size_t)(b * 96 + c)) * 262144;

    for (int i = tid; i < 7700; i += 256) {
        int pz = i / 770;
        int rem = i - pz * 770;
        int r2 = rem / 70;
        int col = rem - r2 * 70;
        int d = d0 + pz - 3, h = h0 + 2 * r2 - 3, w = col - 3;
        float lo = 0.f, hi = 0.f;
        if (((unsigned)d < 64u) && ((unsigned)w < 64u)) {
            int base = d * 4096 + h * 64 + w;
            if ((unsigned)h < 64u) lo = xc[base];
            if ((unsigned)(h + 1) < 64u) hi = xc[base + 64];
        }
        int a = pz * 792 + r2 * 72 + col;
        int aw = ((((a >> 2) ^ ((a >> 5) & 1)) << 2)) | (a & 3);
        tile32[aw] = (u32)f2bf_rne(lo) | ((u32)f2bf_rne(hi) << 16);
    }
    __syncthreads();

    const int tx = tid & 7, ty = (tid >> 3) & 7, tz = tid >> 6;
    float a0[8], a1[8];
#pragma unroll
    for (int i = 0; i < 8; ++i) { a0[i] = 0.f; a1[i] = 0.f; }

    for (int kd = 0; kd < 7; ++kd) {
        const float* Wk = dww + c * 343 + kd * 49;
        const int pz = tz + kd;
#pragma unroll
        for (int pr = 0; pr < 4; ++pr) {
            const int g0 = pz * 198 + (ty + pr) * 18 + (tx << 1);
            u32 rb[16];
#pragma unroll
            for (int k = 0; k < 4; ++k) {
                int g = g0 + k;
                int ga = (g ^ ((g >> 3) & 1)) << 2;
                *(u32x4*)&rb[4 * k] = *(const u32x4*)(tile32 + ga);
            }
            float rlo[16], rhi[16];
#pragma unroll
            for (int t = 0; t < 16; ++t) {
                rlo[t] = __builtin_bit_cast(float, rb[t] << 16);
                rhi[t] = __builtin_bit_cast(float, rb[t]);
            }
#pragma unroll
            for (int kw = 0; kw < 7; ++kw) {
                float wA = Wk[2 * pr * 7 + kw];
#pragma unroll
                for (int i = 0; i < 8; ++i) {
                    a0[i] = fmaf(rlo[kw + i], wA, a0[i]);
                    a1[i] = fmaf(rhi[kw + i], wA, a1[i]);
                }
                if (pr < 3) {
                    float wB = Wk[(2 * pr + 1) * 7 + kw];
#pragma unroll
                    for (int i = 0; i < 8; ++i) a0[i] = fmaf(rhi[kw + i], wB, a0[i]);
                }
                if (pr > 0) {
                    float wC = Wk[(2 * pr - 1) * 7 + kw];
#pragma unroll
                    for (int i = 0; i < 8; ++i) a1[i] = fmaf(rlo[kw + i], wC, a1[i]);
                }
            }
        }
    }

    const float bias = dwb[c];
    const int d = d0 + tz;
    const int hA = h0 + 2 * ty;
    {
        size_t e = ((size_t)(b * 96 + c)) * 262144 + d * 4096 + hA * 64 + 8 * tx;
#pragma unroll
        for (int i = 0; i < 8; ++i) o16[2 * (e + i) + 1] = f2bf_rne(a0[i] + bias);
#pragma unroll
        for (int i = 0; i < 8; ++i) o16[2 * (e + 64 + i) + 1] = f2bf_rne(a1[i] + bias);
    }
    (void)cw;
}

// ---------------------------------------------------------------------------
// K2 v4 + T5: champion mlp3 (paired fp8 gather, LDS H scratch, f32x4
// epilogue) with setprio(1) around the GEMM1 and GEMM2 MFMA clusters.
// Waves are fully independent -> phase diversity -> T5's documented regime.
// launch_bounds(256,4): VGPR must stay <=64 (cliff at 65).
// ---------------------------------------------------------------------------
template<int CWP, int WF>
__global__ __launch_bounds__(256, 4) void mlp3(const void* cwsrc,
                                               const i64* __restrict__ W1L,
                                               const i64* __restrict__ W2L,
                                               const float* __restrict__ B1s,
                                               const float* __restrict__ w1f,
                                               const float* __restrict__ w2f,
                                               const float* __restrict__ lng,
                                               const float* __restrict__ lnb,
                                               const float* __restrict__ b1g,
                                               const float* __restrict__ b2g,
                                               const float* __restrict__ gam,
                                               const float* __restrict__ x,
                                               float* __restrict__ out) {
    __shared__ __align__(16) unsigned char HS[4][2][1152];  // [wave][tile][16 slots * 72B]

    const int tid = threadIdx.x;
    const int wv = tid >> 6, lane = tid & 63;
    const int p = lane & 15, G = lane >> 4;
    const int pos0 = blockIdx.x * 128 + wv * 32;
    const int b = pos0 >> 18, prel0 = pos0 & 262143;
    unsigned char* hsw = &HS[wv][0][0];

    // ---- paired gather: lane (p,G) loads one u16 = fp8 pair (pos0+2p, pos0+2p+1)
    float v0[3][8], v1[3][8];
    if (CWP == 0) {
        const u16* cwp = (const u16*)cwsrc;
#pragma unroll
        for (int kk = 0; kk < 3; ++kk)
#pragma unroll
            for (int m = 0; m < 8; ++m) {
                int c = kk * 32 + G * 8 + m;
                u16 w = cwp[(size_t)c * 262144 + (pos0 >> 1) + p];
                f32x2 pr = __builtin_amdgcn_cvt_pk_f32_fp8((int)(u32)w, false);
                v0[kk][m] = pr[0];
                v1[kk][m] = pr[1];
            }
    } else {
        const u32* ow = (const u32*)cwsrc;
#pragma unroll
        for (int kk = 0; kk < 3; ++kk)
#pragma unroll
            for (int m = 0; m < 8; ++m) {
                int c = kk * 32 + G * 8 + m;
                size_t base = ((size_t)(b * 96 + c)) * 262144 + prel0 + 2 * p;
                v0[kk][m] = bf2f((u16)(ow[base] >> 16));
                v1[kk][m] = bf2f((u16)(ow[base + 1] >> 16));
            }
    }

    // ---- LN stats for both positions (reduce across the 4 G-lanes)
    float s0 = 0.f, sq0 = 0.f, s1 = 0.f, sq1 = 0.f;
#pragma unroll
    for (int kk = 0; kk < 3; ++kk)
#pragma unroll
        for (int m = 0; m < 8; ++m) {
            s0 += v0[kk][m]; sq0 += v0[kk][m] * v0[kk][m];
            s1 += v1[kk][m]; sq1 += v1[kk][m] * v1[kk][m];
        }
    s0 += __shfl_xor(s0, 16); sq0 += __shfl_xor(sq0, 16);
    s0 += __shfl_xor(s0, 32); sq0 += __shfl_xor(sq0, 32);
    s1 += __shfl_xor(s1, 16); sq1 += __shfl_xor(sq1, 16);
    s1 += __shfl_xor(s1, 32); sq1 += __shfl_xor(sq1, 32);
    float mu0 = s0 * (1.f / 96.f);
    float rstd0 = rsqrtf(sq0 * (1.f / 96.f) - mu0 * mu0 + 1e-5f);
    float mu1 = s1 * (1.f / 96.f);
    float rstd1 = rsqrtf(sq1 * (1.f / 96.f) - mu1 * mu1 + 1e-5f);

    i64 aF[2][3];
#pragma unroll
    for (int kk = 0; kk < 3; ++kk) {
        aF[0][kk] = mk64(
            pk4((v0[kk][0] - mu0) * rstd0, (v0[kk][1] - mu0) * rstd0,
                (v0[kk][2] - mu0) * rstd0, (v0[kk][3] - mu0) * rstd0),
            pk4((v0[kk][4] - mu0) * rstd0, (v0[kk][5] - mu0) * rstd0,
                (v0[kk][6] - mu0) * rstd0, (v0[kk][7] - mu0) * rstd0));
        aF[1][kk] = mk64(
            pk4((v1[kk][0] - mu1) * rstd1, (v1[kk][1] - mu1) * rstd1,
                (v1[kk][2] - mu1) * rstd1, (v1[kk][3] - mu1) * rstd1),
            pk4((v1[kk][4] - mu1) * rstd1, (v1[kk][5] - mu1) * rstd1,
                (v1[kk][6] - mu1) * rstd1, (v1[kk][7] - mu1) * rstd1));
    }

    f32x4 acc[2][6];
#pragma unroll
    for (int t = 0; t < 2; ++t)
#pragma unroll
        for (int i = 0; i < 6; ++i) acc[t][i] = f32x4{0.f, 0.f, 0.f, 0.f};

    for (int j = 0; j < 6; ++j) {
        i64 wf[12];
#pragma unroll
        for (int q = 0; q < 12; ++q) {
            if (WF == 0) {
                wf[q] = W1L[(j * 12 + q) * 64 + lane];
            } else {
                int nt = q / 3, kk = q - nt * 3;
                int nn = (j * 4 + nt) * 16 + p;
                int cb = kk * 32 + G * 8;
                wf[q] = mk64(
                    pk4(lng[cb + 0] * w1f[(cb + 0) * 384 + nn], lng[cb + 1] * w1f[(cb + 1) * 384 + nn],
                        lng[cb + 2] * w1f[(cb + 2) * 384 + nn], lng[cb + 3] * w1f[(cb + 3) * 384 + nn]),
                    pk4(lng[cb + 4] * w1f[(cb + 4) * 384 + nn], lng[cb + 5] * w1f[(cb + 5) * 384 + nn],
                        lng[cb + 6] * w1f[(cb + 6) * 384 + nn], lng[cb + 7] * w1f[(cb + 7) * 384 + nn]));
            }
        }
        f32x4 bb[4];
#pragma unroll
        for (int nt = 0; nt < 4; ++nt)
            bb[nt] = *(const f32x4*)&B1s[(j * 4 + nt) * 16 + 4 * G];

#pragma unroll
        for (int t = 0; t < 2; ++t) {
            f32x4 c1[4];
            __builtin_amdgcn_s_setprio(1);         // T5: GEMM1 cluster
#pragma unroll
            for (int nt = 0; nt < 4; ++nt) {
                c1[nt] = f32x4{0.f, 0.f, 0.f, 0.f};
#pragma unroll
                for (int kk = 0; kk < 3; ++kk)
                    c1[nt] = __builtin_amdgcn_mfma_f32_16x16x32_fp8_fp8(wf[nt * 3 + kk], aF[t][kk], c1[nt], 0, 0, 0);
            }
            __builtin_amdgcn_s_setprio(0);
#pragma unroll
            for (int nt = 0; nt < 4; ++nt) {
                float g0 = gelu_fast(c1[nt][0] + bb[nt][0]);
                float g1 = gelu_fast(c1[nt][1] + bb[nt][1]);
                float g2 = gelu_fast(c1[nt][2] + bb[nt][2]);
                float g3 = gelu_fast(c1[nt][3] + bb[nt][3]);
                *(u32*)&hsw[t * 1152 + p * 72 + nt * 16 + 4 * G] = pk4(g0, g1, g2, g3);
            }
        }

        i64 w2r[12];
#pragma unroll
        for (int q = 0; q < 12; ++q) {
            int ct = q >> 1, kkj = q & 1;
            if (WF == 0) {
                w2r[q] = W2L[(ct * 12 + j * 2 + kkj) * 64 + lane];
            } else {
                int cc = ct * 16 + p;
                int nb = (j * 2 + kkj) * 32 + G * 8;
                w2r[q] = mk64(
                    pk4(w2f[(nb + 0) * 96 + cc], w2f[(nb + 1) * 96 + cc],
                        w2f[(nb + 2) * 96 + cc], w2f[(nb + 3) * 96 + cc]),
                    pk4(w2f[(nb + 4) * 96 + cc], w2f[(nb + 5) * 96 + cc],
                        w2f[(nb + 6) * 96 + cc], w2f[(nb + 7) * 96 + cc]));
            }
        }

        asm volatile("s_waitcnt lgkmcnt(0)" ::: "memory");
        __builtin_amdgcn_sched_barrier(0);

        i64 hF[2][2];
#pragma unroll
        for (int t = 0; t < 2; ++t)
#pragma unroll
            for (int kkj = 0; kkj < 2; ++kkj)
                hF[t][kkj] = *(const i64*)&hsw[t * 1152 + p * 72 + kkj * 32 + G * 8];

        __builtin_amdgcn_s_setprio(1);             // T5: GEMM2 cluster
#pragma unroll
        for (int ct = 0; ct < 6; ++ct)
#pragma unroll
            for (int kkj = 0; kkj < 2; ++kkj) {
#pragma unroll
                for (int t = 0; t < 2; ++t)
                    acc[t][ct] = __builtin_amdgcn_mfma_f32_16x16x32_fp8_fp8(hF[t][kkj], w2r[ct * 2 + kkj], acc[t][ct], 0, 0, 0);
            }
        __builtin_amdgcn_s_setprio(0);
    }

    // ---- epilogue: interleave tiles -> contiguous f32x4 at prel0+8G+4k
#pragma unroll
    for (int ct = 0; ct < 6; ++ct) {
        int c = ct * 16 + p;
        float b2c = b2g[c], gc = gam[c];
#pragma unroll
        for (int k = 0; k < 2; ++k) {
            size_t xi = ((size_t)(b * 96 + c)) * 262144 + prel0 + 8 * G + 4 * k;
            f32x4 xv = *(const f32x4*)&x[xi];
            f32x4 o;
            o[0] = (acc[0][ct][2 * k]     + b2c) * gc + xv[0];
            o[1] = (acc[1][ct][2 * k]     + b2c) * gc + xv[1];
            o[2] = (acc[0][ct][2 * k + 1] + b2c) * gc + xv[2];
            o[3] = (acc[1][ct][2 * k + 1] + b2c) * gc + xv[3];
            *(f32x4*)&out[xi] = o;
        }
    }
}

// ---------------------------------------------------------------------------
extern "C" void kernel_launch(void* const* d_in, const int* in_sizes, int n_in,
                              void* d_out, int out_size, void* d_ws, size_t ws_size,
                              hipStream_t stream) {
    const float* x   = (const float*)d_in[0];
    const float* dww = (const float*)d_in[1];
    const float* dwb = (const float*)d_in[2];
    const float* lng = (const float*)d_in[3];
    const float* lnb = (const float*)d_in[4];
    const float* w1  = (const float*)d_in[5];
    const float* b1  = (const float*)d_in[6];
    const float* w2  = (const float*)d_in[7];
    const float* b2  = (const float*)d_in[8];
    const float* gam = (const float*)d_in[9];
    float* out = (float*)d_out;

    // ws: W1L @0 (36864) | W2L (36864) | B1s (1536) | BT @75264 (2408448)
    //     | cw8 @2483712 (50331648 fp8)
    const size_t NEED_W  = 75264;
    const size_t NEED_BT = 75264 + 2408448ull;              // 2,483,712
    const size_t NEED_FULL = NEED_BT + 50331648ull;         // 52,815,360
    const bool wsW  = ws_size >= NEED_W;
    const bool wsBT = ws_size >= NEED_BT;
    const bool wsCW = ws_size >= NEED_FULL;

    i64* W1L = (i64*)d_ws;
    i64* W2L = (i64*)((char*)d_ws + 36864);
    float* B1s = (float*)((char*)d_ws + 73728);
    unsigned char* BT = (unsigned char*)d_ws + 75264;
    unsigned char* cw8 = (unsigned char*)d_ws + 2483712;

    if (wsW)
        hipLaunchKernelGGL(prep_weights, dim3(38), dim3(256), 0, stream,
                           w1, w2, lng, lnb, b1, W1L, W2L, B1s);
    if (wsBT)
        hipLaunchKernelGGL(prep_bt, dim3(1176), dim3(256), 0, stream, dww, BT);

    dim3 g1(16, 96, 2), blkc(512);
    if (wsCW)
        hipLaunchKernelGGL((dwconvM<0>), g1, blkc, 0, stream, x, BT, dwb, cw8, (u16*)d_out);
    else if (wsBT)
        hipLaunchKernelGGL((dwconvM<1>), g1, blkc, 0, stream, x, BT, dwb, cw8, (u16*)d_out);
    else {
        dim3 g1a(64, 96, 2), blka(256);
        hipLaunchKernelGGL((dwconvA<1>), g1a, blka, 0, stream, x, dww, dwb, (u32*)cw8, (u16*)d_out);
    }

    dim3 g2(4096), blk2(256);
    if (wsCW)
        hipLaunchKernelGGL((mlp3<0, 0>), g2, blk2, 0, stream, (const void*)cw8,
                           W1L, W2L, B1s, w1, w2, lng, lnb, b1, b2, gam, x, out);
    else if (wsW)
        hipLaunchKernelGGL((mlp3<1, 0>), g2, blk2, 0, stream, (const void*)d_out,
                           W1L, W2L, B1s, w1, w2, lng, lnb, b1, b2, gam, x, out);
    else
        hipLaunchKernelGGL((mlp3<1, 1>), g2, blk2, 0, stream, (const void*)d_out,
                           W1L, W2L, B1s, w1, w2, lng, lnb, b1, b2, gam, x, out);
}

// Round 20
// 365.426 us; speedup vs baseline: 1.0315x; 1.0153x over previous
//
#include <hip/hip_runtime.h>

typedef unsigned int u32;
typedef unsigned short u16;
typedef unsigned long long u64;
typedef long i64;
typedef float f32x4 __attribute__((ext_vector_type(4)));
typedef float f32x2 __attribute__((ext_vector_type(2)));
typedef u32 u32x4 __attribute__((ext_vector_type(4)));

__device__ __forceinline__ u16 f2bf_rne(float f) {
    return __builtin_bit_cast(u16, (__bf16)f);
}
__device__ __forceinline__ float bf2f(u16 h) {
    return __builtin_bit_cast(float, ((u32)h) << 16);
}
__device__ __forceinline__ float gelu_fast(float v) {
    float t = __builtin_amdgcn_exp2f(v * -2.4554673f);
    return v * __builtin_amdgcn_rcpf(1.f + t);
}
__device__ __forceinline__ i64 mk64(u32 lo, u32 hi) {
    return (i64)(((u64)hi << 32) | (u64)lo);
}
__device__ __forceinline__ u32 pk4(float a, float b, float c, float d) {
    u32 w = (u32)__builtin_amdgcn_cvt_pk_fp8_f32(a, b, 0, false);
    return (u32)__builtin_amdgcn_cvt_pk_fp8_f32(c, d, (int)w, true);
}
__device__ __forceinline__ unsigned char f2fp8(float a) {
    u32 w = (u32)__builtin_amdgcn_cvt_pk_fp8_f32(a, 0.f, 0, false);
    return (unsigned char)(w & 0xffu);
}

// ---------------------------------------------------------------------------
// K0 (merged): MLP weights in MFMA-fragment order + Toeplitz B-frag table.
// Blocks 0..37: W1L/W2L/B1s paths; blocks 38..1213: BT path.
// ---------------------------------------------------------------------------
__global__ void prep_all(const float* __restrict__ w1, const float* __restrict__ w2,
                         const float* __restrict__ dww,
                         const float* __restrict__ lng, const float* __restrict__ lnb,
                         const float* __restrict__ b1,
                         i64* __restrict__ W1L, i64* __restrict__ W2L,
                         float* __restrict__ B1s, unsigned char* __restrict__ BT) {
    if (blockIdx.x < 38) {
        int i = blockIdx.x * 256 + threadIdx.x;
        if (i < 4608) {                               // W1L: 24 j16 * 3 kk * 64 lanes
            int n16 = i / 192, r = i - n16 * 192;
            int kk = r >> 6, lane = r & 63;
            int n = n16 * 16 + (lane & 15);
            int cb = kk * 32 + (lane >> 4) * 8;
            float s0 = lng[cb + 0] * w1[(cb + 0) * 384 + n];
            float s1 = lng[cb + 1] * w1[(cb + 1) * 384 + n];
            float s2 = lng[cb + 2] * w1[(cb + 2) * 384 + n];
            float s3 = lng[cb + 3] * w1[(cb + 3) * 384 + n];
            float s4 = lng[cb + 4] * w1[(cb + 4) * 384 + n];
            float s5 = lng[cb + 5] * w1[(cb + 5) * 384 + n];
            float s6 = lng[cb + 6] * w1[(cb + 6) * 384 + n];
            float s7 = lng[cb + 7] * w1[(cb + 7) * 384 + n];
            W1L[i] = mk64(pk4(s0, s1, s2, s3), pk4(s4, s5, s6, s7));
        } else if (i < 9216) {                        // W2L: 6 ct * 12 jk * 64 lanes
            int e = i - 4608;
            int r = e & 767, lane = r & 63, jk = r >> 6;
            int c = ((e / 768) * 16) + (lane & 15);
            int nb = jk * 32 + (lane >> 4) * 8;
            float s0 = w2[(nb + 0) * 96 + c], s1 = w2[(nb + 1) * 96 + c];
            float s2 = w2[(nb + 2) * 96 + c], s3 = w2[(nb + 3) * 96 + c];
            float s4 = w2[(nb + 4) * 96 + c], s5 = w2[(nb + 5) * 96 + c];
            float s6 = w2[(nb + 6) * 96 + c], s7 = w2[(nb + 7) * 96 + c];
            W2L[e] = mk64(pk4(s0, s1, s2, s3), pk4(s4, s5, s6, s7));
        } else if (i < 9600) {                        // B1s
            int n = i - 9216;
            float s = b1[n];
            for (int c = 0; c < 96; ++c) s += lnb[c] * w1[c * 384 + n];
            B1s[n] = s;
        }
    } else {
        int i = (blockIdx.x - 38) * 256 + threadIdx.x;
        if (i >= 301056) return;                      // 96 * 49 * 64
        int lane = i & 63;
        int tap = (i >> 6) % 49;
        int c = i / 3136;
        int n = lane & 15, kg = lane >> 4;
        const float* wt = dww + c * 343 + tap * 7;
        float e[8];
#pragma unroll
        for (int j = 0; j < 8; ++j) {
            int t = kg * 8 + j - n;
            e[j] = (t >= 0 && t < 7) ? wt[t] : 0.f;
        }
        u32 lo = pk4(e[0], e[1], e[2], e[3]);
        u32 hi = pk4(e[4], e[5], e[6], e[7]);
        *(u32*)&BT[(size_t)i * 8] = lo;
        *(u32*)&BT[(size_t)i * 8 + 4] = hi;
    }
}

// ---------------------------------------------------------------------------
// K1: Toeplitz fp8 MFMA conv — final champion config (R13/R16/R18).
// Wave wv handles planes (wv, wv+8) sequentially. d-tile 16: LDS
// [22 pz][22 row][88 fp8] = 42.6 KB, 3 blocks/CU (62% occupancy measured).
// MERGED z=2 dispatch. fp8 conv-out (WRITE 98->49 MB).
// Rejected by measurement: adjacent-plane pairing (R14/R15, lost a resident
// block), per-batch dispatch split (R12, double tail-drain), setprio (R19,
// null — insufficient wave role-diversity for T5's mechanism).
// ---------------------------------------------------------------------------
template<int PACKED>
__global__ __launch_bounds__(512, 8) void dwconvM(const float* __restrict__ x,
                                                  const unsigned char* __restrict__ BT,
                                                  const float* __restrict__ dwb,
                                                  unsigned char* __restrict__ cw8,
                                                  u16* __restrict__ o16) {
    __shared__ __align__(16) unsigned char tile[42592];   // 22*22*88
    const int tid = threadIdx.x;
    const int bx = blockIdx.x, c = blockIdx.y, b = blockIdx.z;
    const int d0 = (bx >> 2) * 16, h0 = (bx & 3) * 16;
    const float* xc = x + ((size_t)(b * 96 + c)) * 262144;

    // ---- stage fp8 tile: 22 pz x 22 rows x 20 u32 (slot s = w+3)
    for (int i = tid; i < 9680; i += 512) {
        int pz = i / 440;
        int rem = i - pz * 440;
        int row = rem / 20;
        int u = rem - row * 20;
        int d = d0 + pz - 3, h = h0 + row - 3;
        u32 pk = 0;
        if (((unsigned)d < 64u) && ((unsigned)h < 64u)) {
            const float* xr = xc + d * 4096 + h * 64;
            if (u >= 1 && u <= 15) {               // w = 4u-3 .. 4u, all in-range
                float e[4];
                __builtin_memcpy(e, xr + 4 * u - 3, 16);
                pk = pk4(e[0], e[1], e[2], e[3]);
            } else if (u == 0) {                   // only w=0 (slot 3) valid
                pk = pk4(0.f, 0.f, 0.f, xr[0]);
            } else if (u == 16) {                  // w=61,62,63 valid
                pk = pk4(xr[61], xr[62], xr[63], 0.f);
            }                                       // u 17..19 stay zero
        }
        *(u32*)&tile[(pz * 22 + row) * 88 + u * 4] = pk;
    }
    __syncthreads();

    const int lane = tid & 63, wv = tid >> 6;
    const int n = lane & 15, g = lane >> 4;
    const unsigned char* BTl = BT + (size_t)c * 49 * 512 + (size_t)lane * 8;
    const int abase = n * 88 + 8 * g;
    const float bias = dwb[c];

#pragma unroll
    for (int plane = 0; plane < 2; ++plane) {
        const int dd = wv + plane * 8;

        f32x4 acc[4];
#pragma unroll
        for (int i = 0; i < 4; ++i) acc[i] = f32x4{0.f, 0.f, 0.f, 0.f};

        i64 bfC[7], bfN[7];
#pragma unroll
        for (int kh = 0; kh < 7; ++kh)
            bfC[kh] = *(const i64*)(BTl + (size_t)kh * 512);

#pragma unroll
        for (int kd = 0; kd < 7; ++kd) {
#pragma unroll
            for (int kh = 0; kh < 7; ++kh)
                bfN[kh] = (kd < 6) ? *(const i64*)(BTl + (size_t)((kd + 1) * 7 + kh) * 512)
                                   : (i64)0;
            const unsigned char* tb = &tile[(dd + kd) * 1936 + abase];
#pragma unroll
            for (int kh = 0; kh < 7; ++kh) {
                const unsigned char* ab = tb + kh * 88;
#pragma unroll
                for (int wt = 0; wt < 4; ++wt) {
                    i64 af = *(const i64*)(ab + 16 * wt);
                    acc[wt] = __builtin_amdgcn_mfma_f32_16x16x32_fp8_fp8(af, bfC[kh], acc[wt], 0, 0, 0);
                }
            }
#pragma unroll
            for (int kh = 0; kh < 7; ++kh) bfC[kh] = bfN[kh];
        }

        // ---- epilogue: D row m = 4g+q (h), col n (w = wt*16+n)
        const int d = d0 + dd;
#pragma unroll
        for (int wt = 0; wt < 4; ++wt) {
#pragma unroll
            for (int q = 0; q < 4; ++q) {
                int h = h0 + 4 * g + q;
                int w = wt * 16 + n;
                size_t pos = (size_t)b * 262144 + (size_t)d * 4096 + h * 64 + w;
                if (PACKED == 0)
                    cw8[(size_t)c * 524288 + pos] = f2fp8(acc[wt][q] + bias);
                else
                    o16[2 * ((size_t)(b * 96 + c) * 262144 + (size_t)d * 4096 + h * 64 + w) + 1] =
                        f2bf_rne(acc[wt][q] + bias);
            }
        }
    }
}

// ---------------------------------------------------------------------------
// K1-fallback: fp32-FMA conv (R5), used only when ws can't hold BT (PACKED=1).
// ---------------------------------------------------------------------------
template<int PACKED>
__global__ __launch_bounds__(256, 5) void dwconvA(const float* __restrict__ x,
                                                  const float* __restrict__ dww,
                                                  const float* __restrict__ dwb,
                                                  u32* cw, u16* o16) {
    __shared__ u32 tile32[7920];                  // 10 * 792
    const int tid = threadIdx.x;
    const int bx = blockIdx.x, c = blockIdx.y, b = blockIdx.z;
    const int d0 = (bx >> 2) * 4, h0 = (bx & 3) * 16;
    const float* xc = x + ((size_t)(b * 96 + c)) * 262144;

    for (int i = tid; i < 7700; i += 256) {
        int pz = i / 770;
        int rem = i - pz * 770;
        int r2 = rem / 70;
        int col = rem - r2 * 70;
        int d = d0 + pz - 3, h = h0 + 2 * r2 - 3, w = col - 3;
        float lo = 0.f, hi = 0.f;
        if (((unsigned)d < 64u) && ((unsigned)w < 64u)) {
            int base = d * 4096 + h * 64 + w;
            if ((unsigned)h < 64u) lo = xc[base];
            if ((unsigned)(h + 1) < 64u) hi = xc[base + 64];
        }
        int a = pz * 792 + r2 * 72 + col;
        int aw = ((((a >> 2) ^ ((a >> 5) & 1)) << 2)) | (a & 3);
        tile32[aw] = (u32)f2bf_rne(lo) | ((u32)f2bf_rne(hi) << 16);
    }
    __syncthreads();

    const int tx = tid & 7, ty = (tid >> 3) & 7, tz = tid >> 6;
    float a0[8], a1[8];
#pragma unroll
    for (int i = 0; i < 8; ++i) { a0[i] = 0.f; a1[i] = 0.f; }

    for (int kd = 0; kd < 7; ++kd) {
        const float* Wk = dww + c * 343 + kd * 49;
        const int pz = tz + kd;
#pragma unroll
        for (int pr = 0; pr < 4; ++pr) {
            const int g0 = pz * 198 + (ty + pr) * 18 + (tx << 1);
            u32 rb[16];
#pragma unroll
            for (int k = 0; k < 4; ++k) {
                int g = g0 + k;
                int ga = (g ^ ((g >> 3) & 1)) << 2;
                *(u32x4*)&rb[4 * k] = *(const u32x4*)(tile32 + ga);
            }
            float rlo[16], rhi[16];
#pragma unroll
            for (int t = 0; t < 16; ++t) {
                rlo[t] = __builtin_bit_cast(float, rb[t] << 16);
                rhi[t] = __builtin_bit_cast(float, rb[t]);
            }
#pragma unroll
            for (int kw = 0; kw < 7; ++kw) {
                float wA = Wk[2 * pr * 7 + kw];
#pragma unroll
                for (int i = 0; i < 8; ++i) {
                    a0[i] = fmaf(rlo[kw + i], wA, a0[i]);
                    a1[i] = fmaf(rhi[kw + i], wA, a1[i]);
                }
                if (pr < 3) {
                    float wB = Wk[(2 * pr + 1) * 7 + kw];
#pragma unroll
                    for (int i = 0; i < 8; ++i) a0[i] = fmaf(rhi[kw + i], wB, a0[i]);
                }
                if (pr > 0) {
                    float wC = Wk[(2 * pr - 1) * 7 + kw];
#pragma unroll
                    for (int i = 0; i < 8; ++i) a1[i] = fmaf(rlo[kw + i], wC, a1[i]);
                }
            }
        }
    }

    const float bias = dwb[c];
    const int d = d0 + tz;
    const int hA = h0 + 2 * ty;
    {
        size_t e = ((size_t)(b * 96 + c)) * 262144 + d * 4096 + hA * 64 + 8 * tx;
#pragma unroll
        for (int i = 0; i < 8; ++i) o16[2 * (e + i) + 1] = f2bf_rne(a0[i] + bias);
#pragma unroll
        for (int i = 0; i < 8; ++i) o16[2 * (e + 64 + i) + 1] = f2bf_rne(a1[i] + bias);
    }
    (void)cw;
}

// ---------------------------------------------------------------------------
// K2 v4 (final champion): paired-position fp8 gather + per-wave LDS H scratch
// + interleaved f32x4 epilogue. Rejected by measurement: LDS-free shuffle
// (R17, +8 us — shuffles sit on the GEMM1->GEMM2 critical path while LDS
// latency was TLP-hidden), launch_bounds(256,8) (R8, spill disaster),
// setprio (R19, null). launch_bounds(256,4): VGPR must stay <=64.
// ---------------------------------------------------------------------------
template<int CWP, int WF>
__global__ __launch_bounds__(256, 4) void mlp3(const void* cwsrc,
                                               const i64* __restrict__ W1L,
                                               const i64* __restrict__ W2L,
                                               const float* __restrict__ B1s,
                                               const float* __restrict__ w1f,
                                               const float* __restrict__ w2f,
                                               const float* __restrict__ lng,
                                               const float* __restrict__ lnb,
                                               const float* __restrict__ b1g,
                                               const float* __restrict__ b2g,
                                               const float* __restrict__ gam,
                                               const float* __restrict__ x,
                                               float* __restrict__ out) {
    __shared__ __align__(16) unsigned char HS[4][2][1152];  // [wave][tile][16 slots * 72B]

    const int tid = threadIdx.x;
    const int wv = tid >> 6, lane = tid & 63;
    const int p = lane & 15, G = lane >> 4;
    const int pos0 = blockIdx.x * 128 + wv * 32;
    const int b = pos0 >> 18, prel0 = pos0 & 262143;
    unsigned char* hsw = &HS[wv][0][0];

    // ---- paired gather: lane (p,G) loads one u16 = fp8 pair (pos0+2p, pos0+2p+1)
    float v0[3][8], v1[3][8];
    if (CWP == 0) {
        const u16* cwp = (const u16*)cwsrc;
#pragma unroll
        for (int kk = 0; kk < 3; ++kk)
#pragma unroll
            for (int m = 0; m < 8; ++m) {
                int c = kk * 32 + G * 8 + m;
                u16 w = cwp[(size_t)c * 262144 + (pos0 >> 1) + p];
                f32x2 pr = __builtin_amdgcn_cvt_pk_f32_fp8((int)(u32)w, false);
                v0[kk][m] = pr[0];
                v1[kk][m] = pr[1];
            }
    } else {
        const u32* ow = (const u32*)cwsrc;
#pragma unroll
        for (int kk = 0; kk < 3; ++kk)
#pragma unroll
            for (int m = 0; m < 8; ++m) {
                int c = kk * 32 + G * 8 + m;
                size_t base = ((size_t)(b * 96 + c)) * 262144 + prel0 + 2 * p;
                v0[kk][m] = bf2f((u16)(ow[base] >> 16));
                v1[kk][m] = bf2f((u16)(ow[base + 1] >> 16));
            }
    }

    // ---- LN stats for both positions (reduce across the 4 G-lanes)
    float s0 = 0.f, sq0 = 0.f, s1 = 0.f, sq1 = 0.f;
#pragma unroll
    for (int kk = 0; kk < 3; ++kk)
#pragma unroll
        for (int m = 0; m < 8; ++m) {
            s0 += v0[kk][m]; sq0 += v0[kk][m] * v0[kk][m];
            s1 += v1[kk][m]; sq1 += v1[kk][m] * v1[kk][m];
        }
    s0 += __shfl_xor(s0, 16); sq0 += __shfl_xor(sq0, 16);
    s0 += __shfl_xor(s0, 32); sq0 += __shfl_xor(sq0, 32);
    s1 += __shfl_xor(s1, 16); sq1 += __shfl_xor(sq1, 16);
    s1 += __shfl_xor(s1, 32); sq1 += __shfl_xor(sq1, 32);
    float mu0 = s0 * (1.f / 96.f);
    float rstd0 = rsqrtf(sq0 * (1.f / 96.f) - mu0 * mu0 + 1e-5f);
    float mu1 = s1 * (1.f / 96.f);
    float rstd1 = rsqrtf(sq1 * (1.f / 96.f) - mu1 * mu1 + 1e-5f);

    i64 aF[2][3];
#pragma unroll
    for (int kk = 0; kk < 3; ++kk) {
        aF[0][kk] = mk64(
            pk4((v0[kk][0] - mu0) * rstd0, (v0[kk][1] - mu0) * rstd0,
                (v0[kk][2] - mu0) * rstd0, (v0[kk][3] - mu0) * rstd0),
            pk4((v0[kk][4] - mu0) * rstd0, (v0[kk][5] - mu0) * rstd0,
                (v0[kk][6] - mu0) * rstd0, (v0[kk][7] - mu0) * rstd0));
        aF[1][kk] = mk64(
            pk4((v1[kk][0] - mu1) * rstd1, (v1[kk][1] - mu1) * rstd1,
                (v1[kk][2] - mu1) * rstd1, (v1[kk][3] - mu1) * rstd1),
            pk4((v1[kk][4] - mu1) * rstd1, (v1[kk][5] - mu1) * rstd1,
                (v1[kk][6] - mu1) * rstd1, (v1[kk][7] - mu1) * rstd1));
    }

    f32x4 acc[2][6];
#pragma unroll
    for (int t = 0; t < 2; ++t)
#pragma unroll
        for (int i = 0; i < 6; ++i) acc[t][i] = f32x4{0.f, 0.f, 0.f, 0.f};

    for (int j = 0; j < 6; ++j) {
        i64 wf[12];
#pragma unroll
        for (int q = 0; q < 12; ++q) {
            if (WF == 0) {
                wf[q] = W1L[(j * 12 + q) * 64 + lane];
            } else {
                int nt = q / 3, kk = q - nt * 3;
                int nn = (j * 4 + nt) * 16 + p;
                int cb = kk * 32 + G * 8;
                wf[q] = mk64(
                    pk4(lng[cb + 0] * w1f[(cb + 0) * 384 + nn], lng[cb + 1] * w1f[(cb + 1) * 384 + nn],
                        lng[cb + 2] * w1f[(cb + 2) * 384 + nn], lng[cb + 3] * w1f[(cb + 3) * 384 + nn]),
                    pk4(lng[cb + 4] * w1f[(cb + 4) * 384 + nn], lng[cb + 5] * w1f[(cb + 5) * 384 + nn],
                        lng[cb + 6] * w1f[(cb + 6) * 384 + nn], lng[cb + 7] * w1f[(cb + 7) * 384 + nn]));
            }
        }
        f32x4 bb[4];
#pragma unroll
        for (int nt = 0; nt < 4; ++nt)
            bb[nt] = *(const f32x4*)&B1s[(j * 4 + nt) * 16 + 4 * G];

#pragma unroll
        for (int t = 0; t < 2; ++t) {
            f32x4 c1[4];
#pragma unroll
            for (int nt = 0; nt < 4; ++nt) {
                c1[nt] = f32x4{0.f, 0.f, 0.f, 0.f};
#pragma unroll
                for (int kk = 0; kk < 3; ++kk)
                    c1[nt] = __builtin_amdgcn_mfma_f32_16x16x32_fp8_fp8(wf[nt * 3 + kk], aF[t][kk], c1[nt], 0, 0, 0);
            }
#pragma unroll
            for (int nt = 0; nt < 4; ++nt) {
                float g0 = gelu_fast(c1[nt][0] + bb[nt][0]);
                float g1 = gelu_fast(c1[nt][1] + bb[nt][1]);
                float g2 = gelu_fast(c1[nt][2] + bb[nt][2]);
                float g3 = gelu_fast(c1[nt][3] + bb[nt][3]);
                *(u32*)&hsw[t * 1152 + p * 72 + nt * 16 + 4 * G] = pk4(g0, g1, g2, g3);
            }
        }

        i64 w2r[12];
#pragma unroll
        for (int q = 0; q < 12; ++q) {
            int ct = q >> 1, kkj = q & 1;
            if (WF == 0) {
                w2r[q] = W2L[(ct * 12 + j * 2 + kkj) * 64 + lane];
            } else {
                int cc = ct * 16 + p;
                int nb = (j * 2 + kkj) * 32 + G * 8;
                w2r[q] = mk64(
                    pk4(w2f[(nb + 0) * 96 + cc], w2f[(nb + 1) * 96 + cc],
                        w2f[(nb + 2) * 96 + cc], w2f[(nb + 3) * 96 + cc]),
                    pk4(w2f[(nb + 4) * 96 + cc], w2f[(nb + 5) * 96 + cc],
                        w2f[(nb + 6) * 96 + cc], w2f[(nb + 7) * 96 + cc]));
            }
        }

        asm volatile("s_waitcnt lgkmcnt(0)" ::: "memory");
        __builtin_amdgcn_sched_barrier(0);

        i64 hF[2][2];
#pragma unroll
        for (int t = 0; t < 2; ++t)
#pragma unroll
            for (int kkj = 0; kkj < 2; ++kkj)
                hF[t][kkj] = *(const i64*)&hsw[t * 1152 + p * 72 + kkj * 32 + G * 8];

#pragma unroll
        for (int ct = 0; ct < 6; ++ct)
#pragma unroll
            for (int kkj = 0; kkj < 2; ++kkj) {
#pragma unroll
                for (int t = 0; t < 2; ++t)
                    acc[t][ct] = __builtin_amdgcn_mfma_f32_16x16x32_fp8_fp8(hF[t][kkj], w2r[ct * 2 + kkj], acc[t][ct], 0, 0, 0);
            }
    }

    // ---- epilogue: interleave tiles -> contiguous f32x4 at prel0+8G+4k
#pragma unroll
    for (int ct = 0; ct < 6; ++ct) {
        int c = ct * 16 + p;
        float b2c = b2g[c], gc = gam[c];
#pragma unroll
        for (int k = 0; k < 2; ++k) {
            size_t xi = ((size_t)(b * 96 + c)) * 262144 + prel0 + 8 * G + 4 * k;
            f32x4 xv = *(const f32x4*)&x[xi];
            f32x4 o;
            o[0] = (acc[0][ct][2 * k]     + b2c) * gc + xv[0];
            o[1] = (acc[1][ct][2 * k]     + b2c) * gc + xv[1];
            o[2] = (acc[0][ct][2 * k + 1] + b2c) * gc + xv[2];
            o[3] = (acc[1][ct][2 * k + 1] + b2c) * gc + xv[3];
            *(f32x4*)&out[xi] = o;
        }
    }
}

// ---------------------------------------------------------------------------
extern "C" void kernel_launch(void* const* d_in, const int* in_sizes, int n_in,
                              void* d_out, int out_size, void* d_ws, size_t ws_size,
                              hipStream_t stream) {
    const float* x   = (const float*)d_in[0];
    const float* dww = (const float*)d_in[1];
    const float* dwb = (const float*)d_in[2];
    const float* lng = (const float*)d_in[3];
    const float* lnb = (const float*)d_in[4];
    const float* w1  = (const float*)d_in[5];
    const float* b1  = (const float*)d_in[6];
    const float* w2  = (const float*)d_in[7];
    const float* b2  = (const float*)d_in[8];
    const float* gam = (const float*)d_in[9];
    float* out = (float*)d_out;

    // ws: W1L @0 (36864) | W2L (36864) | B1s (1536) | BT @75264 (2408448)
    //     | cw8 @2483712 (50331648 fp8)
    const size_t NEED_W  = 75264;
    const size_t NEED_BT = 75264 + 2408448ull;              // 2,483,712
    const size_t NEED_FULL = NEED_BT + 50331648ull;         // 52,815,360
    const bool wsW  = ws_size >= NEED_W;
    const bool wsBT = ws_size >= NEED_BT;
    const bool wsCW = ws_size >= NEED_FULL;

    i64* W1L = (i64*)d_ws;
    i64* W2L = (i64*)((char*)d_ws + 36864);
    float* B1s = (float*)((char*)d_ws + 73728);
    unsigned char* BT = (unsigned char*)d_ws + 75264;
    unsigned char* cw8 = (unsigned char*)d_ws + 2483712;

    if (wsBT)
        hipLaunchKernelGGL(prep_all, dim3(1214), dim3(256), 0, stream,
                           w1, w2, dww, lng, lnb, b1, W1L, W2L, B1s, BT);
    else if (wsW)
        hipLaunchKernelGGL(prep_all, dim3(38), dim3(256), 0, stream,
                           w1, w2, dww, lng, lnb, b1, W1L, W2L, B1s, BT);

    dim3 g1(16, 96, 2), blkc(512);
    if (wsCW)
        hipLaunchKernelGGL((dwconvM<0>), g1, blkc, 0, stream, x, BT, dwb, cw8, (u16*)d_out);
    else if (wsBT)
        hipLaunchKernelGGL((dwconvM<1>), g1, blkc, 0, stream, x, BT, dwb, cw8, (u16*)d_out);
    else {
        dim3 g1a(64, 96, 2), blka(256);
        hipLaunchKernelGGL((dwconvA<1>), g1a, blka, 0, stream, x, dww, dwb, (u32*)cw8, (u16*)d_out);
    }

    dim3 g2(4096), blk2(256);
    if (wsCW)
        hipLaunchKernelGGL((mlp3<0, 0>), g2, blk2, 0, stream, (const void*)cw8,
                           W1L, W2L, B1s, w1, w2, lng, lnb, b1, b2, gam, x, out);
    else if (wsW)
        hipLaunchKernelGGL((mlp3<1, 0>), g2, blk2, 0, stream, (const void*)d_out,
                           W1L, W2L, B1s, w1, w2, lng, lnb, b1, b2, gam, x, out);
    else
        hipLaunchKernelGGL((mlp3<1, 1>), g2, blk2, 0, stream, (const void*)d_out,
                           W1L, W2L, B1s, w1, w2, lng, lnb, b1, b2, gam, x, out);
}